// Round 12
// baseline (1464.082 us; speedup 1.0000x reference)
//
#include <hip/hip_runtime.h>
#include <hip/hip_bf16.h>
#include <math.h>

// Problem constants
constexpr int BATCH = 8;
constexpr int NPTS  = 2048;
constexpr int CH    = 128;
constexpr int CHO   = 256;
constexpr int NCEN  = 512;
constexpr int NNEI  = 32;   // n_near
constexpr int NTOP  = 11;   // n_stepk + 1
constexpr int NW    = 64;   // bitset words per row (2048/32)

struct Ptr7 { const float* p[7]; };

// ---------------------------------------------------------------- xx = sum(x^2)  (fp32, reference formula)
__global__ __launch_bounds__(256) void xx_kernel(const float* __restrict__ x,
                                                 float* __restrict__ xx) {
    int p = blockIdx.x * 256 + threadIdx.x;
    if (p >= BATCH * NPTS) return;
    const float4* xr = (const float4*)(x + (size_t)p * CH);
    float s = 0.f;
#pragma unroll
    for (int i = 0; i < CH / 4; i++) {
        float4 v = xr[i];
        s += v.x * v.x + v.y * v.y + v.z * v.z + v.w * v.w;
    }
    xx[p] = s;
}

// ---------------------------------------------------------------- D = xx_i + xx_j - 2*dot  (fp32, reference formula)
__global__ __launch_bounds__(256) void dmat_kernel(const float* __restrict__ x,
                                                   const float* __restrict__ xx,
                                                   float* __restrict__ D) {
    __shared__ float As[32][68];
    __shared__ float Bs[32][68];
    int bz = blockIdx.z;
    int i0 = blockIdx.y * 64, j0 = blockIdx.x * 64;
    const float* X = x + (size_t)bz * NPTS * CH;
    int t = threadIdx.x, tx = t & 15, ty = t >> 4;
    int lr = t >> 3, lc = (t & 7) * 4;
    const float* ai0 = X + (size_t)(i0 + lr) * CH;
    const float* ai1 = X + (size_t)(i0 + lr + 32) * CH;
    const float* bj0 = X + (size_t)(j0 + lr) * CH;
    const float* bj1 = X + (size_t)(j0 + lr + 32) * CH;
    float acc[4][4] = {};
    for (int kc = 0; kc < CH; kc += 32) {
        float4 a0 = *(const float4*)(ai0 + kc + lc);
        float4 a1 = *(const float4*)(ai1 + kc + lc);
        float4 b0 = *(const float4*)(bj0 + kc + lc);
        float4 b1 = *(const float4*)(bj1 + kc + lc);
        __syncthreads();
        As[lc + 0][lr] = a0.x; As[lc + 1][lr] = a0.y; As[lc + 2][lr] = a0.z; As[lc + 3][lr] = a0.w;
        As[lc + 0][lr + 32] = a1.x; As[lc + 1][lr + 32] = a1.y; As[lc + 2][lr + 32] = a1.z; As[lc + 3][lr + 32] = a1.w;
        Bs[lc + 0][lr] = b0.x; Bs[lc + 1][lr] = b0.y; Bs[lc + 2][lr] = b0.z; Bs[lc + 3][lr] = b0.w;
        Bs[lc + 0][lr + 32] = b1.x; Bs[lc + 1][lr + 32] = b1.y; Bs[lc + 2][lr + 32] = b1.z; Bs[lc + 3][lr + 32] = b1.w;
        __syncthreads();
#pragma unroll
        for (int kk = 0; kk < 32; kk++) {
            float4 av = *(const float4*)&As[kk][ty * 4];
            float4 bv = *(const float4*)&Bs[kk][tx * 4];
            float a[4] = {av.x, av.y, av.z, av.w};
            float b[4] = {bv.x, bv.y, bv.z, bv.w};
#pragma unroll
            for (int i = 0; i < 4; i++)
#pragma unroll
                for (int j = 0; j < 4; j++) acc[i][j] += a[i] * b[j];
        }
    }
    const float* xxb = xx + bz * NPTS;
    float xi[4], xj[4];
#pragma unroll
    for (int i = 0; i < 4; i++) xi[i] = xxb[i0 + ty * 4 + i];
#pragma unroll
    for (int j = 0; j < 4; j++) xj[j] = xxb[j0 + tx * 4 + j];
#pragma unroll
    for (int i = 0; i < 4; i++) {
        float4 o;
        o.x = xi[i] + xj[0] - 2.f * acc[i][0];
        o.y = xi[i] + xj[1] - 2.f * acc[i][1];
        o.z = xi[i] + xj[2] - 2.f * acc[i][2];
        o.w = xi[i] + xj[3] - 2.f * acc[i][3];
        *(float4*)(D + ((size_t)bz * NPTS + i0 + ty * 4 + i) * NPTS + j0 + tx * 4) = o;
    }
}

// ---------------------------------------------------------------- top-11 on fp32 D (tie -> lowest index) -> adjacency bits
__global__ __launch_bounds__(256) void top11_kernel(const float* __restrict__ D,
                                                    unsigned int* __restrict__ adj) {
    __shared__ float row[NPTS];
    __shared__ float rv[256];
    __shared__ int ri[256];
    __shared__ int picks[NTOP + 1];
    int rid = blockIdx.x;  // b*NPTS + i
    const float* Dr = D + (size_t)rid * NPTS;
    int t = threadIdx.x;
    float4* rp = (float4*)row;
    rp[t] = ((const float4*)Dr)[t];
    rp[t + 256] = ((const float4*)Dr)[t + 256];
    __syncthreads();
    for (int it = 0; it < NTOP; it++) {
        // per-thread scan: j = t + 256k ascending; strict < keeps lowest j on tie
        float bv = row[t];
        int bi = t;
#pragma unroll
        for (int k = 1; k < 8; k++) {
            int j = t + (k << 8);
            float v = row[j];
            if (v < bv) { bv = v; bi = j; }
        }
        rv[t] = bv; ri[t] = bi;
        __syncthreads();
        for (int off = 128; off > 0; off >>= 1) {
            if (t < off) {
                float ov = rv[t + off]; int oi = ri[t + off];
                if (ov < rv[t] || (ov == rv[t] && oi < ri[t])) { rv[t] = ov; ri[t] = oi; }
            }
            __syncthreads();
        }
        if (t == 0) { picks[it] = ri[0]; row[ri[0]] = INFINITY; }
        __syncthreads();
    }
    if (t < NW) {
        unsigned w = 0;
#pragma unroll
        for (int p = 0; p < NTOP; p++) {
            int j = picks[p];
            if ((j >> 5) == t) w |= 1u << (j & 31);
        }
        adj[(size_t)rid * NW + t] = w;
    }
}

// ---------------------------------------------------------------- FPS on fp32 D rows (reference arithmetic)
__global__ __launch_bounds__(256) void fps_kernel(const float* __restrict__ D,
                                                  int* __restrict__ fps_idx) {
    __shared__ float bvs[256];
    __shared__ int bis[256];
    __shared__ int bc;
    int b = blockIdx.x, t = threadIdx.x;
    float mind[8];
#pragma unroll
    for (int r = 0; r < 8; r++) mind[r] = INFINITY;
    int prev = 0;
    if (t == 0) fps_idx[b * NCEN] = 0;
    const float* Db = D + (size_t)b * NPTS * NPTS;
    for (int s = 1; s < NCEN; s++) {
        const float4* rowp = (const float4*)(Db + (size_t)prev * NPTS) + t * 2;
        float4 v0 = rowp[0];
        float4 v1 = rowp[1];
        mind[0] = fminf(mind[0], v0.x); mind[1] = fminf(mind[1], v0.y);
        mind[2] = fminf(mind[2], v0.z); mind[3] = fminf(mind[3], v0.w);
        mind[4] = fminf(mind[4], v1.x); mind[5] = fminf(mind[5], v1.y);
        mind[6] = fminf(mind[6], v1.z); mind[7] = fminf(mind[7], v1.w);
        float bv = -INFINITY; int bj = NPTS;
#pragma unroll
        for (int r = 0; r < 8; r++)
            if (mind[r] > bv) { bv = mind[r]; bj = t * 8 + r; }   // ascending r -> lowest index on tie
        bvs[t] = bv; bis[t] = bj;
        __syncthreads();
        for (int off = 128; off > 0; off >>= 1) {
            if (t < off) {
                if (bvs[t + off] > bvs[t] || (bvs[t + off] == bvs[t] && bis[t + off] < bis[t])) {
                    bvs[t] = bvs[t + off]; bis[t] = bis[t + off];
                }
            }
            __syncthreads();
        }
        if (t == 0) { bc = bis[0]; fps_idx[b * NCEN + s] = bis[0]; }
        __syncthreads();
        prev = bc;
    }
}

// ---------------------------------------------------------------- gather indices
__global__ void make_gather(const int* __restrict__ fps_idx, int* __restrict__ gatherC) {
    int r = blockIdx.x * 256 + threadIdx.x;
    if (r >= BATCH * NCEN) return;
    int b = r >> 9, s = r & 511;
    gatherC[r] = b * NPTS + fps_idx[b * NCEN + s];
}

// ---------------------------------------------------------------- 2-hop reach + top-32 on fp32 D
__global__ __launch_bounds__(256) void reach_top32_kernel(const unsigned int* __restrict__ adj,
                                                          const float* __restrict__ D,
                                                          const int* __restrict__ fps_idx,
                                                          int* __restrict__ idx_sel) {
    __shared__ unsigned adjw[NW], R1[NW], R2[NW];
    __shared__ int lst[NPTS];
    __shared__ float dst[NPTS];
    __shared__ int cnt;
    __shared__ float rv[256];
    __shared__ int rj[256], rp[256];
    __shared__ int sel[NNEI];
    int s = blockIdx.x, b = blockIdx.y, t = threadIdx.x;
    int i = fps_idx[b * NCEN + s];
    const unsigned* arow = adj + ((size_t)(b * NPTS + i)) * NW;
    if (t < NW) { adjw[t] = arow[t]; R1[t] = arow[t]; }
    if (t == 0) cnt = 0;
    __syncthreads();
    if (t < NW) {
        unsigned w = adjw[t];
        while (w) { int bb = __ffs(w) - 1; w &= w - 1; int p = atomicAdd(&cnt, 1); lst[p] = t * 32 + bb; }
    }
    __syncthreads();
    int n1 = cnt;
    {
        int g = t >> 6, lane = t & 63;
        for (int p = g; p < n1; p += 4) {
            unsigned aw = adj[((size_t)(b * NPTS + lst[p])) * NW + lane];
            atomicOr(&R1[lane], aw);
        }
    }
    __syncthreads();
    if (t == 0) cnt = 0;
    __syncthreads();
    if (t < NW) {
        unsigned w = R1[t];
        while (w) { int bb = __ffs(w) - 1; w &= w - 1; int p = atomicAdd(&cnt, 1); lst[p] = t * 32 + bb; }
        R2[t] = adjw[t];
    }
    __syncthreads();
    int n2 = cnt;
    {
        int g = t >> 6, lane = t & 63;
        for (int p = g; p < n2; p += 4) {
            unsigned aw = adj[((size_t)(b * NPTS + lst[p])) * NW + lane];
            atomicOr(&R2[lane], aw);
        }
    }
    __syncthreads();
    if (t == 0) cnt = 0;
    __syncthreads();
    const float* Dr = D + (size_t)(b * NPTS + i) * NPTS;
    if (t < NW) {
        unsigned w = R2[t];
        while (w) {
            int bb = __ffs(w) - 1; w &= w - 1;
            int j = t * 32 + bb;
            int p = atomicAdd(&cnt, 1);
            lst[p] = j; dst[p] = Dr[j];
        }
    }
    __syncthreads();
    int L = cnt;
    int nsel = L < NNEI ? L : NNEI;
    for (int r = 0; r < nsel; r++) {
        float bv = INFINITY; int bj = 0x7fffffff, bp = -1;
        for (int p = t; p < L; p += 256) {
            float v = dst[p]; int j = lst[p];
            if (v < bv || (v == bv && j < bj)) { bv = v; bj = j; bp = p; }
        }
        rv[t] = bv; rj[t] = bj; rp[t] = bp;
        __syncthreads();
        for (int off = 128; off > 0; off >>= 1) {
            if (t < off) {
                if (rv[t + off] < rv[t] || (rv[t + off] == rv[t] && rj[t + off] < rj[t])) {
                    rv[t] = rv[t + off]; rj[t] = rj[t + off]; rp[t] = rp[t + off];
                }
            }
            __syncthreads();
        }
        if (t == 0) { sel[r] = rj[0]; dst[rp[0]] = INFINITY; }
        __syncthreads();
    }
    if (t == 0 && nsel < NNEI) {
        int r = nsel;
        for (int j = 0; j < NPTS && r < NNEI; j++)
            if (!((R2[j >> 5] >> (j & 31)) & 1)) sel[r++] = j;
    }
    __syncthreads();
    if (t < NNEI) idx_sel[((size_t)(b * NCEN + s)) * NNEI + t] = sel[t];
}

// ---------------------------------------------------------------- 64x64 fp32 GEMM tile
template <int KSIZE, bool RELU>
__device__ __forceinline__ void gemm_tile64(const float* __restrict__ A, int lda,
                                            const int* __restrict__ gather,
                                            const float* __restrict__ W, int ldw,
                                            const float* __restrict__ bias,
                                            float* __restrict__ Out, int ldo) {
    __shared__ float As[32][68];
    __shared__ float Ws[32][68];
    int t = threadIdx.x;
    int tx = t & 15, ty = t >> 4;
    int lr = t >> 3, lc = (t & 7) * 4;
    const float* ar0 = A + (size_t)(gather ? gather[lr] : lr) * lda;
    const float* ar1 = A + (size_t)(gather ? gather[lr + 32] : lr + 32) * lda;
    float acc[4][4] = {};
    for (int kc = 0; kc < KSIZE; kc += 32) {
        float4 a0 = *(const float4*)(ar0 + kc + lc);
        float4 a1 = *(const float4*)(ar1 + kc + lc);
        float4 w0 = *(const float4*)(W + (size_t)(kc + lr) * ldw + lc);
        float4 w1 = *(const float4*)(W + (size_t)(kc + lr) * ldw + lc + 32);
        __syncthreads();
        As[lc + 0][lr] = a0.x; As[lc + 1][lr] = a0.y; As[lc + 2][lr] = a0.z; As[lc + 3][lr] = a0.w;
        As[lc + 0][lr + 32] = a1.x; As[lc + 1][lr + 32] = a1.y; As[lc + 2][lr + 32] = a1.z; As[lc + 3][lr + 32] = a1.w;
        *(float4*)&Ws[lr][lc] = w0;
        *(float4*)&Ws[lr][lc + 32] = w1;
        __syncthreads();
#pragma unroll
        for (int kk = 0; kk < 32; kk++) {
            float4 av = *(const float4*)&As[kk][ty * 4];
            float4 wv = *(const float4*)&Ws[kk][tx * 4];
            float a[4] = {av.x, av.y, av.z, av.w};
            float w[4] = {wv.x, wv.y, wv.z, wv.w};
#pragma unroll
            for (int i = 0; i < 4; i++)
#pragma unroll
                for (int j = 0; j < 4; j++) acc[i][j] += a[i] * w[j];
        }
    }
#pragma unroll
    for (int i = 0; i < 4; i++) {
        int r = ty * 4 + i;
        float4 o;
        o.x = acc[i][0] + bias[tx * 4 + 0];
        o.y = acc[i][1] + bias[tx * 4 + 1];
        o.z = acc[i][2] + bias[tx * 4 + 2];
        o.w = acc[i][3] + bias[tx * 4 + 3];
        if (RELU) {
            o.x = fmaxf(o.x, 0.f); o.y = fmaxf(o.y, 0.f);
            o.z = fmaxf(o.z, 0.f); o.w = fmaxf(o.w, 0.f);
        }
        *(float4*)(Out + (size_t)r * ldo + tx * 4) = o;
    }
}

// ---------------------------------------------------------------- GEMM wrappers
__global__ __launch_bounds__(256) void kvproj_kernel(Ptr7 feats, const float* __restrict__ awk,
                                                     const float* __restrict__ abk,
                                                     const float* __restrict__ awv,
                                                     const float* __restrict__ abv,
                                                     float* __restrict__ ktab,
                                                     float* __restrict__ vtab) {
    int v = blockIdx.z, ct = blockIdx.y, rt = blockIdx.x;
    bool isv = ct >= 2;
    int c2 = ct & 1;
    const float* A = feats.p[v] + (size_t)rt * 64 * CH;
    const float* W = (isv ? awv : awk) + (size_t)v * CH * CH + c2 * 64;
    const float* bias = (isv ? abv : abk) + v * CH + c2 * 64;
    float* Out = (isv ? vtab : ktab) + (size_t)v * (BATCH * NPTS) * CH + (size_t)rt * 64 * CH + c2 * 64;
    gemm_tile64<CH, false>(A, CH, nullptr, W, CH, bias, Out, CH);
}

__global__ __launch_bounds__(256) void qproj_kernel(Ptr7 feats, const float* __restrict__ awq,
                                                    const float* __restrict__ abq,
                                                    const int* __restrict__ gatherC,
                                                    float* __restrict__ qtab) {
    int v = blockIdx.z, ct = blockIdx.y, rt = blockIdx.x;
    gemm_tile64<CH, false>(feats.p[v], CH, gatherC + rt * 64,
                           awq + (size_t)v * CH * CH + ct * 64, CH,
                           abq + v * CH + ct * 64,
                           qtab + ((size_t)v * (BATCH * NCEN) + rt * 64) * CH + ct * 64, CH);
}

__global__ __launch_bounds__(256) void mlp1_kernel(const float* __restrict__ otab,
                                                   const float* __restrict__ mw1,
                                                   const float* __restrict__ mb1,
                                                   float* __restrict__ htab) {
    int v = blockIdx.z, ct = blockIdx.y, rt = blockIdx.x;
    gemm_tile64<CH, true>(otab + ((size_t)v * (BATCH * NCEN) + rt * 64) * CH, CH, nullptr,
                          mw1 + (size_t)v * CH * CHO + ct * 64, CHO,
                          mb1 + v * CHO + ct * 64,
                          htab + ((size_t)v * (BATCH * NCEN) + rt * 64) * CHO + ct * 64, CHO);
}

__global__ __launch_bounds__(256) void mlp2_kernel(const float* __restrict__ htab,
                                                   const float* __restrict__ mw2,
                                                   const float* __restrict__ mb2,
                                                   float* __restrict__ out) {
    int v = blockIdx.z, ct = blockIdx.y, rt = blockIdx.x;
    gemm_tile64<CHO, true>(htab + ((size_t)v * (BATCH * NCEN) + rt * 64) * CHO, CHO, nullptr,
                           mw2 + (size_t)v * CHO * CHO + ct * 64, CHO,
                           mb2 + v * CHO + ct * 64,
                           out + ((size_t)v * (BATCH * NCEN) + rt * 64) * CHO + ct * 64, CHO);
}

// ---------------------------------------------------------------- attention
__global__ __launch_bounds__(256) void attn_kernel(const float* __restrict__ qtab,
                                                   const float* __restrict__ ktab,
                                                   const float* __restrict__ vtab,
                                                   const int* __restrict__ idx_sel,
                                                   float* __restrict__ otab) {
    __shared__ float q_s[4][CH];
    __shared__ float attn_s[4][NNEI];
    __shared__ int jj_s[4][NNEI];
    int v = blockIdx.y;
    int t = threadIdx.x, w = t >> 6, lane = t & 63;
    int cg = blockIdx.x * 4 + w;
    int b = cg >> 9, s = cg & 511;
    const float* qr = qtab + ((size_t)v * (BATCH * NCEN) + cg) * CH;
    *(float2*)&q_s[w][lane * 2] = *(const float2*)(qr + lane * 2);
    if (lane < NNEI) jj_s[w][lane] = idx_sel[((size_t)(b * NCEN + s)) * NNEI + lane];
    __syncthreads();
    if (lane < NNEI) {
        int j = jj_s[w][lane];
        const float* kr = ktab + ((size_t)v * (BATCH * NPTS) + b * NPTS + j) * CH;
        float acc = 0.f;
#pragma unroll
        for (int c4 = 0; c4 < CH / 4; c4++) {
            float4 qv = *(const float4*)&q_s[w][c4 * 4];
            float4 kv = *(const float4*)(kr + c4 * 4);
            acc += qv.x * kv.x + qv.y * kv.y + qv.z * kv.z + qv.w * kv.w;
        }
        float sc = acc * 0.08838834764831845f;  // 1/sqrt(128)
        float m = sc;
#pragma unroll
        for (int off = 16; off > 0; off >>= 1) m = fmaxf(m, __shfl_xor(m, off, 32));
        float e = expf(sc - m);
        float sum = e;
#pragma unroll
        for (int off = 16; off > 0; off >>= 1) sum += __shfl_xor(sum, off, 32);
        attn_s[w][lane] = e / sum;
    }
    __syncthreads();
    float2 o = {0.f, 0.f};
    const float* vbase = vtab + ((size_t)v * (BATCH * NPTS) + b * NPTS) * CH;
    for (int tt = 0; tt < NNEI; tt++) {
        int j = jj_s[w][tt];
        float a = attn_s[w][tt];
        float2 vv = *(const float2*)(vbase + (size_t)j * CH + lane * 2);
        o.x += a * vv.x;
        o.y += a * vv.y;
    }
    *(float2*)(otab + ((size_t)v * (BATCH * NCEN) + cg) * CH + lane * 2) = o;
}

// ---------------------------------------------------------------- launch
extern "C" void kernel_launch(void* const* d_in, const int* in_sizes, int n_in,
                              void* d_out, int out_size, void* d_ws, size_t ws_size,
                              hipStream_t stream) {
    (void)in_sizes; (void)n_in; (void)out_size;
    Ptr7 feats;
    for (int i = 0; i < 7; i++) feats.p[i] = (const float*)d_in[i];
    const float* awq = (const float*)d_in[7];
    const float* abq = (const float*)d_in[8];
    const float* awk = (const float*)d_in[9];
    const float* abk = (const float*)d_in[10];
    const float* awv = (const float*)d_in[11];
    const float* abv = (const float*)d_in[12];
    const float* mw1 = (const float*)d_in[13];
    const float* mb1 = (const float*)d_in[14];
    const float* mw2 = (const float*)d_in[15];
    const float* mb2 = (const float*)d_in[16];
    const float* xyz = feats.p[0];

    char* ws = (char*)d_ws;
    size_t SZ_D = (size_t)BATCH * NPTS * NPTS * 4;       // 134 MB
    float* D = (float*)ws;
    float* ktab = (float*)ws;                            // overlays D (dead by then)
    float* vtab = (float*)(ws + (size_t)7 * BATCH * NPTS * CH * 4);
    size_t off = SZ_D;
    float* xx = (float*)(ws + off); off += (size_t)BATCH * NPTS * 4;
    unsigned* adjb = (unsigned*)(ws + off); off += (size_t)BATCH * NPTS * NW * 4;
    int* fpsidx = (int*)(ws + off); off += (size_t)BATCH * NCEN * 4;
    int* idxsel = (int*)(ws + off); off += (size_t)BATCH * NCEN * NNEI * 4;
    int* gatherC = (int*)(ws + off); off += (size_t)BATCH * NCEN * 4;
    float* qtab = (float*)(ws + off); off += (size_t)7 * BATCH * NCEN * CH * 4;
    float* otab = (float*)(ws + off); off += (size_t)7 * BATCH * NCEN * CH * 4;
    float* htab = (float*)(ws + off); off += (size_t)7 * BATCH * NCEN * CHO * 4;
    if (ws_size < off) return;

    xx_kernel<<<dim3((BATCH * NPTS + 255) / 256), dim3(256), 0, stream>>>(xyz, xx);
    dmat_kernel<<<dim3(NPTS / 64, NPTS / 64, BATCH), dim3(256), 0, stream>>>(xyz, xx, D);
    top11_kernel<<<dim3(BATCH * NPTS), dim3(256), 0, stream>>>(D, adjb);
    fps_kernel<<<dim3(BATCH), dim3(256), 0, stream>>>(D, fpsidx);
    make_gather<<<dim3((BATCH * NCEN + 255) / 256), dim3(256), 0, stream>>>(fpsidx, gatherC);
    reach_top32_kernel<<<dim3(NCEN, BATCH), dim3(256), 0, stream>>>(adjb, D, fpsidx, idxsel);
    // D dead: ktab/vtab overlay it
    kvproj_kernel<<<dim3(BATCH * NPTS / 64, 4, 7), dim3(256), 0, stream>>>(feats, awk, abk, awv, abv, ktab, vtab);
    qproj_kernel<<<dim3(BATCH * NCEN / 64, 2, 7), dim3(256), 0, stream>>>(feats, awq, abq, gatherC, qtab);
    attn_kernel<<<dim3(BATCH * NCEN / 4, 7), dim3(256), 0, stream>>>(qtab, ktab, vtab, idxsel, otab);
    mlp1_kernel<<<dim3(BATCH * NCEN / 64, 4, 7), dim3(256), 0, stream>>>(otab, mw1, mb1, htab);
    mlp2_kernel<<<dim3(BATCH * NCEN / 64, 4, 7), dim3(256), 0, stream>>>(htab, mw2, mb2, (float*)d_out);
}

// Round 13
// 1276.745 us; speedup vs baseline: 1.1467x; 1.1467x over previous
//
#include <hip/hip_runtime.h>
#include <hip/hip_bf16.h>
#include <math.h>

// Problem constants
constexpr int BATCH = 8;
constexpr int NPTS  = 2048;
constexpr int CH    = 128;
constexpr int CHO   = 256;
constexpr int NCEN  = 512;
constexpr int NNEI  = 32;   // n_near
constexpr int NTOP  = 11;   // n_stepk + 1
constexpr int NW    = 64;   // bitset words per row (2048/32)

struct Ptr7 { const float* p[7]; };

// ---------------------------------------------------------------- xx = sum(x^2)  (fp32, reference formula)
__global__ __launch_bounds__(256) void xx_kernel(const float* __restrict__ x,
                                                 float* __restrict__ xx) {
    int p = blockIdx.x * 256 + threadIdx.x;
    if (p >= BATCH * NPTS) return;
    const float4* xr = (const float4*)(x + (size_t)p * CH);
    float s = 0.f;
#pragma unroll
    for (int i = 0; i < CH / 4; i++) {
        float4 v = xr[i];
        s += v.x * v.x + v.y * v.y + v.z * v.z + v.w * v.w;
    }
    xx[p] = s;
}

// ---------------------------------------------------------------- D = xx_i + xx_j - 2*dot  (fp32, reference formula)
__global__ __launch_bounds__(256) void dmat_kernel(const float* __restrict__ x,
                                                   const float* __restrict__ xx,
                                                   float* __restrict__ D) {
    __shared__ float As[32][68];
    __shared__ float Bs[32][68];
    int bz = blockIdx.z;
    int i0 = blockIdx.y * 64, j0 = blockIdx.x * 64;
    const float* X = x + (size_t)bz * NPTS * CH;
    int t = threadIdx.x, tx = t & 15, ty = t >> 4;
    int lr = t >> 3, lc = (t & 7) * 4;
    const float* ai0 = X + (size_t)(i0 + lr) * CH;
    const float* ai1 = X + (size_t)(i0 + lr + 32) * CH;
    const float* bj0 = X + (size_t)(j0 + lr) * CH;
    const float* bj1 = X + (size_t)(j0 + lr + 32) * CH;
    float acc[4][4] = {};
    for (int kc = 0; kc < CH; kc += 32) {
        float4 a0 = *(const float4*)(ai0 + kc + lc);
        float4 a1 = *(const float4*)(ai1 + kc + lc);
        float4 b0 = *(const float4*)(bj0 + kc + lc);
        float4 b1 = *(const float4*)(bj1 + kc + lc);
        __syncthreads();
        As[lc + 0][lr] = a0.x; As[lc + 1][lr] = a0.y; As[lc + 2][lr] = a0.z; As[lc + 3][lr] = a0.w;
        As[lc + 0][lr + 32] = a1.x; As[lc + 1][lr + 32] = a1.y; As[lc + 2][lr + 32] = a1.z; As[lc + 3][lr + 32] = a1.w;
        Bs[lc + 0][lr] = b0.x; Bs[lc + 1][lr] = b0.y; Bs[lc + 2][lr] = b0.z; Bs[lc + 3][lr] = b0.w;
        Bs[lc + 0][lr + 32] = b1.x; Bs[lc + 1][lr + 32] = b1.y; Bs[lc + 2][lr + 32] = b1.z; Bs[lc + 3][lr + 32] = b1.w;
        __syncthreads();
#pragma unroll
        for (int kk = 0; kk < 32; kk++) {
            float4 av = *(const float4*)&As[kk][ty * 4];
            float4 bv = *(const float4*)&Bs[kk][tx * 4];
            float a[4] = {av.x, av.y, av.z, av.w};
            float b[4] = {bv.x, bv.y, bv.z, bv.w};
#pragma unroll
            for (int i = 0; i < 4; i++)
#pragma unroll
                for (int j = 0; j < 4; j++) acc[i][j] += a[i] * b[j];
        }
    }
    const float* xxb = xx + bz * NPTS;
    float xi[4], xj[4];
#pragma unroll
    for (int i = 0; i < 4; i++) xi[i] = xxb[i0 + ty * 4 + i];
#pragma unroll
    for (int j = 0; j < 4; j++) xj[j] = xxb[j0 + tx * 4 + j];
#pragma unroll
    for (int i = 0; i < 4; i++) {
        float4 o;
        o.x = xi[i] + xj[0] - 2.f * acc[i][0];
        o.y = xi[i] + xj[1] - 2.f * acc[i][1];
        o.z = xi[i] + xj[2] - 2.f * acc[i][2];
        o.w = xi[i] + xj[3] - 2.f * acc[i][3];
        *(float4*)(D + ((size_t)bz * NPTS + i0 + ty * 4 + i) * NPTS + j0 + tx * 4) = o;
    }
}

// ---------------------------------------------------------------- top-11 on fp32 D (tie -> lowest index) -> adjacency bits
__global__ __launch_bounds__(256) void top11_kernel(const float* __restrict__ D,
                                                    unsigned int* __restrict__ adj) {
    __shared__ float row[NPTS];
    __shared__ float rv[256];
    __shared__ int ri[256];
    __shared__ int picks[NTOP + 1];
    int rid = blockIdx.x;  // b*NPTS + i
    const float* Dr = D + (size_t)rid * NPTS;
    int t = threadIdx.x;
    float4* rp = (float4*)row;
    rp[t] = ((const float4*)Dr)[t];
    rp[t + 256] = ((const float4*)Dr)[t + 256];
    __syncthreads();
    for (int it = 0; it < NTOP; it++) {
        float bv = row[t];
        int bi = t;
#pragma unroll
        for (int k = 1; k < 8; k++) {
            int j = t + (k << 8);
            float v = row[j];
            if (v < bv) { bv = v; bi = j; }
        }
        rv[t] = bv; ri[t] = bi;
        __syncthreads();
        for (int off = 128; off > 0; off >>= 1) {
            if (t < off) {
                float ov = rv[t + off]; int oi = ri[t + off];
                if (ov < rv[t] || (ov == rv[t] && oi < ri[t])) { rv[t] = ov; ri[t] = oi; }
            }
            __syncthreads();
        }
        if (t == 0) { picks[it] = ri[0]; row[ri[0]] = INFINITY; }
        __syncthreads();
    }
    if (t < NW) {
        unsigned w = 0;
#pragma unroll
        for (int p = 0; p < NTOP; p++) {
            int j = picks[p];
            if ((j >> 5) == t) w |= 1u << (j & 31);
        }
        adj[(size_t)rid * NW + t] = w;
    }
}

// ---------------------------------------------------------------- FPS: one wave per batch, zero barriers
// Exact reference semantics: mind = fminf(mind, D[prev]); argmax, first (lowest-index) max on ties.
__global__ __launch_bounds__(64) void fps_kernel(const float* __restrict__ D,
                                                 int* __restrict__ fps_idx) {
    int b = blockIdx.x, lane = threadIdx.x;
    float mind[32];
#pragma unroll
    for (int r = 0; r < 32; r++) mind[r] = INFINITY;
    int prev = 0;
    if (lane == 0) fps_idx[b * NCEN] = 0;
    const float* Db = D + (size_t)b * NPTS * NPTS;
    for (int s = 1; s < NCEN; s++) {
        const float4* rowp = (const float4*)(Db + (size_t)prev * NPTS);
        float bv = -INFINITY; int bj = NPTS;
#pragma unroll
        for (int k = 0; k < 8; k++) {
            float4 v = rowp[lane + 64 * k];          // coalesced: 64 lanes x 16B
            int j0 = 4 * (lane + 64 * k);
            float m0 = fminf(mind[4 * k + 0], v.x); mind[4 * k + 0] = m0;
            float m1 = fminf(mind[4 * k + 1], v.y); mind[4 * k + 1] = m1;
            float m2 = fminf(mind[4 * k + 2], v.z); mind[4 * k + 2] = m2;
            float m3 = fminf(mind[4 * k + 3], v.w); mind[4 * k + 3] = m3;
            // ascending j within lane -> strict > keeps lowest index on ties
            if (m0 > bv) { bv = m0; bj = j0 + 0; }
            if (m1 > bv) { bv = m1; bj = j0 + 1; }
            if (m2 > bv) { bv = m2; bj = j0 + 2; }
            if (m3 > bv) { bv = m3; bj = j0 + 3; }
        }
        // 64-lane butterfly argmax, tie -> lowest index
#pragma unroll
        for (int off = 32; off > 0; off >>= 1) {
            float ov = __shfl_xor(bv, off);
            int oj = __shfl_xor(bj, off);
            if (ov > bv || (ov == bv && oj < bj)) { bv = ov; bj = oj; }
        }
        if (lane == 0) fps_idx[b * NCEN + s] = bj;
        prev = bj;   // all lanes agree
    }
}

// ---------------------------------------------------------------- gather indices
__global__ void make_gather(const int* __restrict__ fps_idx, int* __restrict__ gatherC) {
    int r = blockIdx.x * 256 + threadIdx.x;
    if (r >= BATCH * NCEN) return;
    int b = r >> 9, s = r & 511;
    gatherC[r] = b * NPTS + fps_idx[b * NCEN + s];
}

// ---------------------------------------------------------------- 2-hop reach + top-32 on fp32 D
__global__ __launch_bounds__(256) void reach_top32_kernel(const unsigned int* __restrict__ adj,
                                                          const float* __restrict__ D,
                                                          const int* __restrict__ fps_idx,
                                                          int* __restrict__ idx_sel) {
    __shared__ unsigned adjw[NW], R1[NW], R2[NW];
    __shared__ int lst[NPTS];
    __shared__ float dst[NPTS];
    __shared__ int cnt;
    __shared__ float rv[256];
    __shared__ int rj[256], rp[256];
    __shared__ int sel[NNEI];
    int s = blockIdx.x, b = blockIdx.y, t = threadIdx.x;
    int i = fps_idx[b * NCEN + s];
    const unsigned* arow = adj + ((size_t)(b * NPTS + i)) * NW;
    if (t < NW) { adjw[t] = arow[t]; R1[t] = arow[t]; }
    if (t == 0) cnt = 0;
    __syncthreads();
    if (t < NW) {
        unsigned w = adjw[t];
        while (w) { int bb = __ffs(w) - 1; w &= w - 1; int p = atomicAdd(&cnt, 1); lst[p] = t * 32 + bb; }
    }
    __syncthreads();
    int n1 = cnt;
    {
        int g = t >> 6, lane = t & 63;
        for (int p = g; p < n1; p += 4) {
            unsigned aw = adj[((size_t)(b * NPTS + lst[p])) * NW + lane];
            atomicOr(&R1[lane], aw);
        }
    }
    __syncthreads();
    if (t == 0) cnt = 0;
    __syncthreads();
    if (t < NW) {
        unsigned w = R1[t];
        while (w) { int bb = __ffs(w) - 1; w &= w - 1; int p = atomicAdd(&cnt, 1); lst[p] = t * 32 + bb; }
        R2[t] = adjw[t];
    }
    __syncthreads();
    int n2 = cnt;
    {
        int g = t >> 6, lane = t & 63;
        for (int p = g; p < n2; p += 4) {
            unsigned aw = adj[((size_t)(b * NPTS + lst[p])) * NW + lane];
            atomicOr(&R2[lane], aw);
        }
    }
    __syncthreads();
    if (t == 0) cnt = 0;
    __syncthreads();
    const float* Dr = D + (size_t)(b * NPTS + i) * NPTS;
    if (t < NW) {
        unsigned w = R2[t];
        while (w) {
            int bb = __ffs(w) - 1; w &= w - 1;
            int j = t * 32 + bb;
            int p = atomicAdd(&cnt, 1);
            lst[p] = j; dst[p] = Dr[j];
        }
    }
    __syncthreads();
    int L = cnt;
    int nsel = L < NNEI ? L : NNEI;
    for (int r = 0; r < nsel; r++) {
        float bv = INFINITY; int bj = 0x7fffffff, bp = -1;
        for (int p = t; p < L; p += 256) {
            float v = dst[p]; int j = lst[p];
            if (v < bv || (v == bv && j < bj)) { bv = v; bj = j; bp = p; }
        }
        rv[t] = bv; rj[t] = bj; rp[t] = bp;
        __syncthreads();
        for (int off = 128; off > 0; off >>= 1) {
            if (t < off) {
                if (rv[t + off] < rv[t] || (rv[t + off] == rv[t] && rj[t + off] < rj[t])) {
                    rv[t] = rv[t + off]; rj[t] = rj[t + off]; rp[t] = rp[t + off];
                }
            }
            __syncthreads();
        }
        if (t == 0) { sel[r] = rj[0]; dst[rp[0]] = INFINITY; }
        __syncthreads();
    }
    if (t == 0 && nsel < NNEI) {
        int r = nsel;
        for (int j = 0; j < NPTS && r < NNEI; j++)
            if (!((R2[j >> 5] >> (j & 31)) & 1)) sel[r++] = j;
    }
    __syncthreads();
    if (t < NNEI) idx_sel[((size_t)(b * NCEN + s)) * NNEI + t] = sel[t];
}

// ---------------------------------------------------------------- 64x64 fp32 GEMM tile
template <int KSIZE, bool RELU>
__device__ __forceinline__ void gemm_tile64(const float* __restrict__ A, int lda,
                                            const int* __restrict__ gather,
                                            const float* __restrict__ W, int ldw,
                                            const float* __restrict__ bias,
                                            float* __restrict__ Out, int ldo) {
    __shared__ float As[32][68];
    __shared__ float Ws[32][68];
    int t = threadIdx.x;
    int tx = t & 15, ty = t >> 4;
    int lr = t >> 3, lc = (t & 7) * 4;
    const float* ar0 = A + (size_t)(gather ? gather[lr] : lr) * lda;
    const float* ar1 = A + (size_t)(gather ? gather[lr + 32] : lr + 32) * lda;
    float acc[4][4] = {};
    for (int kc = 0; kc < KSIZE; kc += 32) {
        float4 a0 = *(const float4*)(ar0 + kc + lc);
        float4 a1 = *(const float4*)(ar1 + kc + lc);
        float4 w0 = *(const float4*)(W + (size_t)(kc + lr) * ldw + lc);
        float4 w1 = *(const float4*)(W + (size_t)(kc + lr) * ldw + lc + 32);
        __syncthreads();
        As[lc + 0][lr] = a0.x; As[lc + 1][lr] = a0.y; As[lc + 2][lr] = a0.z; As[lc + 3][lr] = a0.w;
        As[lc + 0][lr + 32] = a1.x; As[lc + 1][lr + 32] = a1.y; As[lc + 2][lr + 32] = a1.z; As[lc + 3][lr + 32] = a1.w;
        *(float4*)&Ws[lr][lc] = w0;
        *(float4*)&Ws[lr][lc + 32] = w1;
        __syncthreads();
#pragma unroll
        for (int kk = 0; kk < 32; kk++) {
            float4 av = *(const float4*)&As[kk][ty * 4];
            float4 wv = *(const float4*)&Ws[kk][tx * 4];
            float a[4] = {av.x, av.y, av.z, av.w};
            float w[4] = {wv.x, wv.y, wv.z, wv.w};
#pragma unroll
            for (int i = 0; i < 4; i++)
#pragma unroll
                for (int j = 0; j < 4; j++) acc[i][j] += a[i] * w[j];
        }
    }
#pragma unroll
    for (int i = 0; i < 4; i++) {
        int r = ty * 4 + i;
        float4 o;
        o.x = acc[i][0] + bias[tx * 4 + 0];
        o.y = acc[i][1] + bias[tx * 4 + 1];
        o.z = acc[i][2] + bias[tx * 4 + 2];
        o.w = acc[i][3] + bias[tx * 4 + 3];
        if (RELU) {
            o.x = fmaxf(o.x, 0.f); o.y = fmaxf(o.y, 0.f);
            o.z = fmaxf(o.z, 0.f); o.w = fmaxf(o.w, 0.f);
        }
        *(float4*)(Out + (size_t)r * ldo + tx * 4) = o;
    }
}

// ---------------------------------------------------------------- GEMM wrappers
__global__ __launch_bounds__(256) void kvproj_kernel(Ptr7 feats, const float* __restrict__ awk,
                                                     const float* __restrict__ abk,
                                                     const float* __restrict__ awv,
                                                     const float* __restrict__ abv,
                                                     float* __restrict__ ktab,
                                                     float* __restrict__ vtab) {
    int v = blockIdx.z, ct = blockIdx.y, rt = blockIdx.x;
    bool isv = ct >= 2;
    int c2 = ct & 1;
    const float* A = feats.p[v] + (size_t)rt * 64 * CH;
    const float* W = (isv ? awv : awk) + (size_t)v * CH * CH + c2 * 64;
    const float* bias = (isv ? abv : abk) + v * CH + c2 * 64;
    float* Out = (isv ? vtab : ktab) + (size_t)v * (BATCH * NPTS) * CH + (size_t)rt * 64 * CH + c2 * 64;
    gemm_tile64<CH, false>(A, CH, nullptr, W, CH, bias, Out, CH);
}

__global__ __launch_bounds__(256) void qproj_kernel(Ptr7 feats, const float* __restrict__ awq,
                                                    const float* __restrict__ abq,
                                                    const int* __restrict__ gatherC,
                                                    float* __restrict__ qtab) {
    int v = blockIdx.z, ct = blockIdx.y, rt = blockIdx.x;
    gemm_tile64<CH, false>(feats.p[v], CH, gatherC + rt * 64,
                           awq + (size_t)v * CH * CH + ct * 64, CH,
                           abq + v * CH + ct * 64,
                           qtab + ((size_t)v * (BATCH * NCEN) + rt * 64) * CH + ct * 64, CH);
}

__global__ __launch_bounds__(256) void mlp1_kernel(const float* __restrict__ otab,
                                                   const float* __restrict__ mw1,
                                                   const float* __restrict__ mb1,
                                                   float* __restrict__ htab) {
    int v = blockIdx.z, ct = blockIdx.y, rt = blockIdx.x;
    gemm_tile64<CH, true>(otab + ((size_t)v * (BATCH * NCEN) + rt * 64) * CH, CH, nullptr,
                          mw1 + (size_t)v * CH * CHO + ct * 64, CHO,
                          mb1 + v * CHO + ct * 64,
                          htab + ((size_t)v * (BATCH * NCEN) + rt * 64) * CHO + ct * 64, CHO);
}

__global__ __launch_bounds__(256) void mlp2_kernel(const float* __restrict__ htab,
                                                   const float* __restrict__ mw2,
                                                   const float* __restrict__ mb2,
                                                   float* __restrict__ out) {
    int v = blockIdx.z, ct = blockIdx.y, rt = blockIdx.x;
    gemm_tile64<CHO, true>(htab + ((size_t)v * (BATCH * NCEN) + rt * 64) * CHO, CHO, nullptr,
                           mw2 + (size_t)v * CHO * CHO + ct * 64, CHO,
                           mb2 + v * CHO + ct * 64,
                           out + ((size_t)v * (BATCH * NCEN) + rt * 64) * CHO + ct * 64, CHO);
}

// ---------------------------------------------------------------- attention
__global__ __launch_bounds__(256) void attn_kernel(const float* __restrict__ qtab,
                                                   const float* __restrict__ ktab,
                                                   const float* __restrict__ vtab,
                                                   const int* __restrict__ idx_sel,
                                                   float* __restrict__ otab) {
    __shared__ float q_s[4][CH];
    __shared__ float attn_s[4][NNEI];
    __shared__ int jj_s[4][NNEI];
    int v = blockIdx.y;
    int t = threadIdx.x, w = t >> 6, lane = t & 63;
    int cg = blockIdx.x * 4 + w;
    int b = cg >> 9, s = cg & 511;
    const float* qr = qtab + ((size_t)v * (BATCH * NCEN) + cg) * CH;
    *(float2*)&q_s[w][lane * 2] = *(const float2*)(qr + lane * 2);
    if (lane < NNEI) jj_s[w][lane] = idx_sel[((size_t)(b * NCEN + s)) * NNEI + lane];
    __syncthreads();
    if (lane < NNEI) {
        int j = jj_s[w][lane];
        const float* kr = ktab + ((size_t)v * (BATCH * NPTS) + b * NPTS + j) * CH;
        float acc = 0.f;
#pragma unroll
        for (int c4 = 0; c4 < CH / 4; c4++) {
            float4 qv = *(const float4*)&q_s[w][c4 * 4];
            float4 kv = *(const float4*)(kr + c4 * 4);
            acc += qv.x * kv.x + qv.y * kv.y + qv.z * kv.z + qv.w * kv.w;
        }
        float sc = acc * 0.08838834764831845f;  // 1/sqrt(128)
        float m = sc;
#pragma unroll
        for (int off = 16; off > 0; off >>= 1) m = fmaxf(m, __shfl_xor(m, off, 32));
        float e = expf(sc - m);
        float sum = e;
#pragma unroll
        for (int off = 16; off > 0; off >>= 1) sum += __shfl_xor(sum, off, 32);
        attn_s[w][lane] = e / sum;
    }
    __syncthreads();
    float2 o = {0.f, 0.f};
    const float* vbase = vtab + ((size_t)v * (BATCH * NPTS) + b * NPTS) * CH;
    for (int tt = 0; tt < NNEI; tt++) {
        int j = jj_s[w][tt];
        float a = attn_s[w][tt];
        float2 vv = *(const float2*)(vbase + (size_t)j * CH + lane * 2);
        o.x += a * vv.x;
        o.y += a * vv.y;
    }
    *(float2*)(otab + ((size_t)v * (BATCH * NCEN) + cg) * CH + lane * 2) = o;
}

// ---------------------------------------------------------------- launch
extern "C" void kernel_launch(void* const* d_in, const int* in_sizes, int n_in,
                              void* d_out, int out_size, void* d_ws, size_t ws_size,
                              hipStream_t stream) {
    (void)in_sizes; (void)n_in; (void)out_size;
    Ptr7 feats;
    for (int i = 0; i < 7; i++) feats.p[i] = (const float*)d_in[i];
    const float* awq = (const float*)d_in[7];
    const float* abq = (const float*)d_in[8];
    const float* awk = (const float*)d_in[9];
    const float* abk = (const float*)d_in[10];
    const float* awv = (const float*)d_in[11];
    const float* abv = (const float*)d_in[12];
    const float* mw1 = (const float*)d_in[13];
    const float* mb1 = (const float*)d_in[14];
    const float* mw2 = (const float*)d_in[15];
    const float* mb2 = (const float*)d_in[16];
    const float* xyz = feats.p[0];

    char* ws = (char*)d_ws;
    size_t SZ_D = (size_t)BATCH * NPTS * NPTS * 4;       // 134 MB
    float* D = (float*)ws;
    float* ktab = (float*)ws;                            // overlays D (dead by then)
    float* vtab = (float*)(ws + (size_t)7 * BATCH * NPTS * CH * 4);
    size_t off = SZ_D;
    float* xx = (float*)(ws + off); off += (size_t)BATCH * NPTS * 4;
    unsigned* adjb = (unsigned*)(ws + off); off += (size_t)BATCH * NPTS * NW * 4;
    int* fpsidx = (int*)(ws + off); off += (size_t)BATCH * NCEN * 4;
    int* idxsel = (int*)(ws + off); off += (size_t)BATCH * NCEN * NNEI * 4;
    int* gatherC = (int*)(ws + off); off += (size_t)BATCH * NCEN * 4;
    float* qtab = (float*)(ws + off); off += (size_t)7 * BATCH * NCEN * CH * 4;
    float* otab = (float*)(ws + off); off += (size_t)7 * BATCH * NCEN * CH * 4;
    float* htab = (float*)(ws + off); off += (size_t)7 * BATCH * NCEN * CHO * 4;
    if (ws_size < off) return;

    xx_kernel<<<dim3((BATCH * NPTS + 255) / 256), dim3(256), 0, stream>>>(xyz, xx);
    dmat_kernel<<<dim3(NPTS / 64, NPTS / 64, BATCH), dim3(256), 0, stream>>>(xyz, xx, D);
    top11_kernel<<<dim3(BATCH * NPTS), dim3(256), 0, stream>>>(D, adjb);
    fps_kernel<<<dim3(BATCH), dim3(64), 0, stream>>>(D, fpsidx);
    make_gather<<<dim3((BATCH * NCEN + 255) / 256), dim3(256), 0, stream>>>(fpsidx, gatherC);
    reach_top32_kernel<<<dim3(NCEN, BATCH), dim3(256), 0, stream>>>(adjb, D, fpsidx, idxsel);
    // D dead: ktab/vtab overlay it
    kvproj_kernel<<<dim3(BATCH * NPTS / 64, 4, 7), dim3(256), 0, stream>>>(feats, awk, abk, awv, abv, ktab, vtab);
    qproj_kernel<<<dim3(BATCH * NCEN / 64, 2, 7), dim3(256), 0, stream>>>(feats, awq, abq, gatherC, qtab);
    attn_kernel<<<dim3(BATCH * NCEN / 4, 7), dim3(256), 0, stream>>>(qtab, ktab, vtab, idxsel, otab);
    mlp1_kernel<<<dim3(BATCH * NCEN / 64, 4, 7), dim3(256), 0, stream>>>(otab, mw1, mb1, htab);
    mlp2_kernel<<<dim3(BATCH * NCEN / 64, 4, 7), dim3(256), 0, stream>>>(htab, mw2, mb2, (float*)d_out);
}

// Round 14
// 1161.526 us; speedup vs baseline: 1.2605x; 1.0992x over previous
//
#include <hip/hip_runtime.h>
#include <hip/hip_bf16.h>
#include <math.h>

// Problem constants
constexpr int BATCH = 8;
constexpr int NPTS  = 2048;
constexpr int CH    = 128;
constexpr int CHO   = 256;
constexpr int NCEN  = 512;
constexpr int NNEI  = 32;   // n_near
constexpr int NTOP  = 11;   // n_stepk + 1
constexpr int NW    = 64;   // bitset words per row (2048/32)

struct Ptr7 { const float* p[7]; };

// ---------------------------------------------------------------- xx = sum(x^2)  (fp32, reference formula)
__global__ __launch_bounds__(256) void xx_kernel(const float* __restrict__ x,
                                                 float* __restrict__ xx) {
    int p = blockIdx.x * 256 + threadIdx.x;
    if (p >= BATCH * NPTS) return;
    const float4* xr = (const float4*)(x + (size_t)p * CH);
    float s = 0.f;
#pragma unroll
    for (int i = 0; i < CH / 4; i++) {
        float4 v = xr[i];
        s += v.x * v.x + v.y * v.y + v.z * v.z + v.w * v.w;
    }
    xx[p] = s;
}

// ---------------------------------------------------------------- D = xx_i + xx_j - 2*dot  (fp32, reference formula)
__global__ __launch_bounds__(256) void dmat_kernel(const float* __restrict__ x,
                                                   const float* __restrict__ xx,
                                                   float* __restrict__ D) {
    __shared__ float As[32][68];
    __shared__ float Bs[32][68];
    int bz = blockIdx.z;
    int i0 = blockIdx.y * 64, j0 = blockIdx.x * 64;
    const float* X = x + (size_t)bz * NPTS * CH;
    int t = threadIdx.x, tx = t & 15, ty = t >> 4;
    int lr = t >> 3, lc = (t & 7) * 4;
    const float* ai0 = X + (size_t)(i0 + lr) * CH;
    const float* ai1 = X + (size_t)(i0 + lr + 32) * CH;
    const float* bj0 = X + (size_t)(j0 + lr) * CH;
    const float* bj1 = X + (size_t)(j0 + lr + 32) * CH;
    float acc[4][4] = {};
    for (int kc = 0; kc < CH; kc += 32) {
        float4 a0 = *(const float4*)(ai0 + kc + lc);
        float4 a1 = *(const float4*)(ai1 + kc + lc);
        float4 b0 = *(const float4*)(bj0 + kc + lc);
        float4 b1 = *(const float4*)(bj1 + kc + lc);
        __syncthreads();
        As[lc + 0][lr] = a0.x; As[lc + 1][lr] = a0.y; As[lc + 2][lr] = a0.z; As[lc + 3][lr] = a0.w;
        As[lc + 0][lr + 32] = a1.x; As[lc + 1][lr + 32] = a1.y; As[lc + 2][lr + 32] = a1.z; As[lc + 3][lr + 32] = a1.w;
        Bs[lc + 0][lr] = b0.x; Bs[lc + 1][lr] = b0.y; Bs[lc + 2][lr] = b0.z; Bs[lc + 3][lr] = b0.w;
        Bs[lc + 0][lr + 32] = b1.x; Bs[lc + 1][lr + 32] = b1.y; Bs[lc + 2][lr + 32] = b1.z; Bs[lc + 3][lr + 32] = b1.w;
        __syncthreads();
#pragma unroll
        for (int kk = 0; kk < 32; kk++) {
            float4 av = *(const float4*)&As[kk][ty * 4];
            float4 bv = *(const float4*)&Bs[kk][tx * 4];
            float a[4] = {av.x, av.y, av.z, av.w};
            float b[4] = {bv.x, bv.y, bv.z, bv.w};
#pragma unroll
            for (int i = 0; i < 4; i++)
#pragma unroll
                for (int j = 0; j < 4; j++) acc[i][j] += a[i] * b[j];
        }
    }
    const float* xxb = xx + bz * NPTS;
    float xi[4], xj[4];
#pragma unroll
    for (int i = 0; i < 4; i++) xi[i] = xxb[i0 + ty * 4 + i];
#pragma unroll
    for (int j = 0; j < 4; j++) xj[j] = xxb[j0 + tx * 4 + j];
#pragma unroll
    for (int i = 0; i < 4; i++) {
        float4 o;
        o.x = xi[i] + xj[0] - 2.f * acc[i][0];
        o.y = xi[i] + xj[1] - 2.f * acc[i][1];
        o.z = xi[i] + xj[2] - 2.f * acc[i][2];
        o.w = xi[i] + xj[3] - 2.f * acc[i][3];
        *(float4*)(D + ((size_t)bz * NPTS + i0 + ty * 4 + i) * NPTS + j0 + tx * 4) = o;
    }
}

// ---------------------------------------------------------------- merged: fps (blocks 0..7) + top-11 (blocks 8..)
// fps: one wave, zero barriers, all 8 row-loads hoisted (single HBM round-trip per step).
// top11: per-row iterative min-select on fp32 D, tie -> lowest index.
__global__ __launch_bounds__(256) void knn_fps_kernel(const float* __restrict__ D,
                                                      unsigned int* __restrict__ adj,
                                                      int* __restrict__ fps_idx) {
    if (blockIdx.x < BATCH) {
        // ---------------- FPS branch ----------------
        int lane = threadIdx.x;
        if (lane >= 64) return;                      // one wave; no barriers in this path
        int b = blockIdx.x;
        float mind[32];
#pragma unroll
        for (int r = 0; r < 32; r++) mind[r] = INFINITY;
        int prev = 0;
        if (lane == 0) fps_idx[b * NCEN] = 0;
        const float* Db = D + (size_t)b * NPTS * NPTS;
        for (int s = 1; s < NCEN; s++) {
            const float4* rowp = (const float4*)(Db + (size_t)prev * NPTS);
            // hoist ALL loads: 8 independent dwordx4, one waitcnt
            float4 v0 = rowp[lane + 0 * 64];
            float4 v1 = rowp[lane + 1 * 64];
            float4 v2 = rowp[lane + 2 * 64];
            float4 v3 = rowp[lane + 3 * 64];
            float4 v4 = rowp[lane + 4 * 64];
            float4 v5 = rowp[lane + 5 * 64];
            float4 v6 = rowp[lane + 6 * 64];
            float4 v7 = rowp[lane + 7 * 64];
            float bv = -INFINITY; int bj = NPTS;
            float4 vv[8] = {v0, v1, v2, v3, v4, v5, v6, v7};
#pragma unroll
            for (int k = 0; k < 8; k++) {
                int j0 = 4 * (lane + 64 * k);
                float m0 = fminf(mind[4 * k + 0], vv[k].x); mind[4 * k + 0] = m0;
                float m1 = fminf(mind[4 * k + 1], vv[k].y); mind[4 * k + 1] = m1;
                float m2 = fminf(mind[4 * k + 2], vv[k].z); mind[4 * k + 2] = m2;
                float m3 = fminf(mind[4 * k + 3], vv[k].w); mind[4 * k + 3] = m3;
                // ascending j -> strict > keeps lowest index on ties
                if (m0 > bv) { bv = m0; bj = j0 + 0; }
                if (m1 > bv) { bv = m1; bj = j0 + 1; }
                if (m2 > bv) { bv = m2; bj = j0 + 2; }
                if (m3 > bv) { bv = m3; bj = j0 + 3; }
            }
#pragma unroll
            for (int off = 32; off > 0; off >>= 1) {
                float ov = __shfl_xor(bv, off);
                int oj = __shfl_xor(bj, off);
                if (ov > bv || (ov == bv && oj < bj)) { bv = ov; bj = oj; }
            }
            if (lane == 0) fps_idx[b * NCEN + s] = bj;
            prev = bj;   // all lanes agree
        }
        return;
    }
    // ---------------- top-11 branch ----------------
    __shared__ float row[NPTS];
    __shared__ float rv[256];
    __shared__ int ri[256];
    __shared__ int picks[NTOP + 1];
    int rid = blockIdx.x - BATCH;  // b*NPTS + i
    const float* Dr = D + (size_t)rid * NPTS;
    int t = threadIdx.x;
    float4* rp = (float4*)row;
    rp[t] = ((const float4*)Dr)[t];
    rp[t + 256] = ((const float4*)Dr)[t + 256];
    __syncthreads();
    for (int it = 0; it < NTOP; it++) {
        float bv = row[t];
        int bi = t;
#pragma unroll
        for (int k = 1; k < 8; k++) {
            int j = t + (k << 8);
            float v = row[j];
            if (v < bv) { bv = v; bi = j; }
        }
        rv[t] = bv; ri[t] = bi;
        __syncthreads();
        for (int off = 128; off > 0; off >>= 1) {
            if (t < off) {
                float ov = rv[t + off]; int oi = ri[t + off];
                if (ov < rv[t] || (ov == rv[t] && oi < ri[t])) { rv[t] = ov; ri[t] = oi; }
            }
            __syncthreads();
        }
        if (t == 0) { picks[it] = ri[0]; row[ri[0]] = INFINITY; }
        __syncthreads();
    }
    if (t < NW) {
        unsigned w = 0;
#pragma unroll
        for (int p = 0; p < NTOP; p++) {
            int j = picks[p];
            if ((j >> 5) == t) w |= 1u << (j & 31);
        }
        adj[(size_t)rid * NW + t] = w;
    }
}

// ---------------------------------------------------------------- gather indices
__global__ void make_gather(const int* __restrict__ fps_idx, int* __restrict__ gatherC) {
    int r = blockIdx.x * 256 + threadIdx.x;
    if (r >= BATCH * NCEN) return;
    int b = r >> 9, s = r & 511;
    gatherC[r] = b * NPTS + fps_idx[b * NCEN + s];
}

// ---------------------------------------------------------------- 2-hop reach + top-32 on fp32 D
__global__ __launch_bounds__(256) void reach_top32_kernel(const unsigned int* __restrict__ adj,
                                                          const float* __restrict__ D,
                                                          const int* __restrict__ fps_idx,
                                                          int* __restrict__ idx_sel) {
    __shared__ unsigned adjw[NW], R1[NW], R2[NW];
    __shared__ int lst[NPTS];
    __shared__ float dst[NPTS];
    __shared__ int cnt;
    __shared__ float rv[256];
    __shared__ int rj[256], rp[256];
    __shared__ int sel[NNEI];
    int s = blockIdx.x, b = blockIdx.y, t = threadIdx.x;
    int i = fps_idx[b * NCEN + s];
    const unsigned* arow = adj + ((size_t)(b * NPTS + i)) * NW;
    if (t < NW) { adjw[t] = arow[t]; R1[t] = arow[t]; }
    if (t == 0) cnt = 0;
    __syncthreads();
    if (t < NW) {
        unsigned w = adjw[t];
        while (w) { int bb = __ffs(w) - 1; w &= w - 1; int p = atomicAdd(&cnt, 1); lst[p] = t * 32 + bb; }
    }
    __syncthreads();
    int n1 = cnt;
    {
        int g = t >> 6, lane = t & 63;
        for (int p = g; p < n1; p += 4) {
            unsigned aw = adj[((size_t)(b * NPTS + lst[p])) * NW + lane];
            atomicOr(&R1[lane], aw);
        }
    }
    __syncthreads();
    if (t == 0) cnt = 0;
    __syncthreads();
    if (t < NW) {
        unsigned w = R1[t];
        while (w) { int bb = __ffs(w) - 1; w &= w - 1; int p = atomicAdd(&cnt, 1); lst[p] = t * 32 + bb; }
        R2[t] = adjw[t];
    }
    __syncthreads();
    int n2 = cnt;
    {
        int g = t >> 6, lane = t & 63;
        for (int p = g; p < n2; p += 4) {
            unsigned aw = adj[((size_t)(b * NPTS + lst[p])) * NW + lane];
            atomicOr(&R2[lane], aw);
        }
    }
    __syncthreads();
    if (t == 0) cnt = 0;
    __syncthreads();
    const float* Dr = D + (size_t)(b * NPTS + i) * NPTS;
    if (t < NW) {
        unsigned w = R2[t];
        while (w) {
            int bb = __ffs(w) - 1; w &= w - 1;
            int j = t * 32 + bb;
            int p = atomicAdd(&cnt, 1);
            lst[p] = j; dst[p] = Dr[j];
        }
    }
    __syncthreads();
    int L = cnt;
    int nsel = L < NNEI ? L : NNEI;
    for (int r = 0; r < nsel; r++) {
        float bv = INFINITY; int bj = 0x7fffffff, bp = -1;
        for (int p = t; p < L; p += 256) {
            float v = dst[p]; int j = lst[p];
            if (v < bv || (v == bv && j < bj)) { bv = v; bj = j; bp = p; }
        }
        rv[t] = bv; rj[t] = bj; rp[t] = bp;
        __syncthreads();
        for (int off = 128; off > 0; off >>= 1) {
            if (t < off) {
                if (rv[t + off] < rv[t] || (rv[t + off] == rv[t] && rj[t + off] < rj[t])) {
                    rv[t] = rv[t + off]; rj[t] = rj[t + off]; rp[t] = rp[t + off];
                }
            }
            __syncthreads();
        }
        if (t == 0) { sel[r] = rj[0]; dst[rp[0]] = INFINITY; }
        __syncthreads();
    }
    if (t == 0 && nsel < NNEI) {
        int r = nsel;
        for (int j = 0; j < NPTS && r < NNEI; j++)
            if (!((R2[j >> 5] >> (j & 31)) & 1)) sel[r++] = j;
    }
    __syncthreads();
    if (t < NNEI) idx_sel[((size_t)(b * NCEN + s)) * NNEI + t] = sel[t];
}

// ---------------------------------------------------------------- 64x64 fp32 GEMM tile
template <int KSIZE, bool RELU>
__device__ __forceinline__ void gemm_tile64(const float* __restrict__ A, int lda,
                                            const int* __restrict__ gather,
                                            const float* __restrict__ W, int ldw,
                                            const float* __restrict__ bias,
                                            float* __restrict__ Out, int ldo) {
    __shared__ float As[32][68];
    __shared__ float Ws[32][68];
    int t = threadIdx.x;
    int tx = t & 15, ty = t >> 4;
    int lr = t >> 3, lc = (t & 7) * 4;
    const float* ar0 = A + (size_t)(gather ? gather[lr] : lr) * lda;
    const float* ar1 = A + (size_t)(gather ? gather[lr + 32] : lr + 32) * lda;
    float acc[4][4] = {};
    for (int kc = 0; kc < KSIZE; kc += 32) {
        float4 a0 = *(const float4*)(ar0 + kc + lc);
        float4 a1 = *(const float4*)(ar1 + kc + lc);
        float4 w0 = *(const float4*)(W + (size_t)(kc + lr) * ldw + lc);
        float4 w1 = *(const float4*)(W + (size_t)(kc + lr) * ldw + lc + 32);
        __syncthreads();
        As[lc + 0][lr] = a0.x; As[lc + 1][lr] = a0.y; As[lc + 2][lr] = a0.z; As[lc + 3][lr] = a0.w;
        As[lc + 0][lr + 32] = a1.x; As[lc + 1][lr + 32] = a1.y; As[lc + 2][lr + 32] = a1.z; As[lc + 3][lr + 32] = a1.w;
        *(float4*)&Ws[lr][lc] = w0;
        *(float4*)&Ws[lr][lc + 32] = w1;
        __syncthreads();
#pragma unroll
        for (int kk = 0; kk < 32; kk++) {
            float4 av = *(const float4*)&As[kk][ty * 4];
            float4 wv = *(const float4*)&Ws[kk][tx * 4];
            float a[4] = {av.x, av.y, av.z, av.w};
            float w[4] = {wv.x, wv.y, wv.z, wv.w};
#pragma unroll
            for (int i = 0; i < 4; i++)
#pragma unroll
                for (int j = 0; j < 4; j++) acc[i][j] += a[i] * w[j];
        }
    }
#pragma unroll
    for (int i = 0; i < 4; i++) {
        int r = ty * 4 + i;
        float4 o;
        o.x = acc[i][0] + bias[tx * 4 + 0];
        o.y = acc[i][1] + bias[tx * 4 + 1];
        o.z = acc[i][2] + bias[tx * 4 + 2];
        o.w = acc[i][3] + bias[tx * 4 + 3];
        if (RELU) {
            o.x = fmaxf(o.x, 0.f); o.y = fmaxf(o.y, 0.f);
            o.z = fmaxf(o.z, 0.f); o.w = fmaxf(o.w, 0.f);
        }
        *(float4*)(Out + (size_t)r * ldo + tx * 4) = o;
    }
}

// ---------------------------------------------------------------- GEMM wrappers
__global__ __launch_bounds__(256) void kvproj_kernel(Ptr7 feats, const float* __restrict__ awk,
                                                     const float* __restrict__ abk,
                                                     const float* __restrict__ awv,
                                                     const float* __restrict__ abv,
                                                     float* __restrict__ ktab,
                                                     float* __restrict__ vtab) {
    int v = blockIdx.z, ct = blockIdx.y, rt = blockIdx.x;
    bool isv = ct >= 2;
    int c2 = ct & 1;
    const float* A = feats.p[v] + (size_t)rt * 64 * CH;
    const float* W = (isv ? awv : awk) + (size_t)v * CH * CH + c2 * 64;
    const float* bias = (isv ? abv : abk) + v * CH + c2 * 64;
    float* Out = (isv ? vtab : ktab) + (size_t)v * (BATCH * NPTS) * CH + (size_t)rt * 64 * CH + c2 * 64;
    gemm_tile64<CH, false>(A, CH, nullptr, W, CH, bias, Out, CH);
}

__global__ __launch_bounds__(256) void qproj_kernel(Ptr7 feats, const float* __restrict__ awq,
                                                    const float* __restrict__ abq,
                                                    const int* __restrict__ gatherC,
                                                    float* __restrict__ qtab) {
    int v = blockIdx.z, ct = blockIdx.y, rt = blockIdx.x;
    gemm_tile64<CH, false>(feats.p[v], CH, gatherC + rt * 64,
                           awq + (size_t)v * CH * CH + ct * 64, CH,
                           abq + v * CH + ct * 64,
                           qtab + ((size_t)v * (BATCH * NCEN) + rt * 64) * CH + ct * 64, CH);
}

__global__ __launch_bounds__(256) void mlp1_kernel(const float* __restrict__ otab,
                                                   const float* __restrict__ mw1,
                                                   const float* __restrict__ mb1,
                                                   float* __restrict__ htab) {
    int v = blockIdx.z, ct = blockIdx.y, rt = blockIdx.x;
    gemm_tile64<CH, true>(otab + ((size_t)v * (BATCH * NCEN) + rt * 64) * CH, CH, nullptr,
                          mw1 + (size_t)v * CH * CHO + ct * 64, CHO,
                          mb1 + v * CHO + ct * 64,
                          htab + ((size_t)v * (BATCH * NCEN) + rt * 64) * CHO + ct * 64, CHO);
}

__global__ __launch_bounds__(256) void mlp2_kernel(const float* __restrict__ htab,
                                                   const float* __restrict__ mw2,
                                                   const float* __restrict__ mb2,
                                                   float* __restrict__ out) {
    int v = blockIdx.z, ct = blockIdx.y, rt = blockIdx.x;
    gemm_tile64<CHO, true>(htab + ((size_t)v * (BATCH * NCEN) + rt * 64) * CHO, CHO, nullptr,
                           mw2 + (size_t)v * CHO * CHO + ct * 64, CHO,
                           mb2 + v * CHO + ct * 64,
                           out + ((size_t)v * (BATCH * NCEN) + rt * 64) * CHO + ct * 64, CHO);
}

// ---------------------------------------------------------------- attention
__global__ __launch_bounds__(256) void attn_kernel(const float* __restrict__ qtab,
                                                   const float* __restrict__ ktab,
                                                   const float* __restrict__ vtab,
                                                   const int* __restrict__ idx_sel,
                                                   float* __restrict__ otab) {
    __shared__ float q_s[4][CH];
    __shared__ float attn_s[4][NNEI];
    __shared__ int jj_s[4][NNEI];
    int v = blockIdx.y;
    int t = threadIdx.x, w = t >> 6, lane = t & 63;
    int cg = blockIdx.x * 4 + w;
    int b = cg >> 9, s = cg & 511;
    const float* qr = qtab + ((size_t)v * (BATCH * NCEN) + cg) * CH;
    *(float2*)&q_s[w][lane * 2] = *(const float2*)(qr + lane * 2);
    if (lane < NNEI) jj_s[w][lane] = idx_sel[((size_t)(b * NCEN + s)) * NNEI + lane];
    __syncthreads();
    if (lane < NNEI) {
        int j = jj_s[w][lane];
        const float* kr = ktab + ((size_t)v * (BATCH * NPTS) + b * NPTS + j) * CH;
        float acc = 0.f;
#pragma unroll
        for (int c4 = 0; c4 < CH / 4; c4++) {
            float4 qv = *(const float4*)&q_s[w][c4 * 4];
            float4 kv = *(const float4*)(kr + c4 * 4);
            acc += qv.x * kv.x + qv.y * kv.y + qv.z * kv.z + qv.w * kv.w;
        }
        float sc = acc * 0.08838834764831845f;  // 1/sqrt(128)
        float m = sc;
#pragma unroll
        for (int off = 16; off > 0; off >>= 1) m = fmaxf(m, __shfl_xor(m, off, 32));
        float e = expf(sc - m);
        float sum = e;
#pragma unroll
        for (int off = 16; off > 0; off >>= 1) sum += __shfl_xor(sum, off, 32);
        attn_s[w][lane] = e / sum;
    }
    __syncthreads();
    float2 o = {0.f, 0.f};
    const float* vbase = vtab + ((size_t)v * (BATCH * NPTS) + b * NPTS) * CH;
    for (int tt = 0; tt < NNEI; tt++) {
        int j = jj_s[w][tt];
        float a = attn_s[w][tt];
        float2 vv = *(const float2*)(vbase + (size_t)j * CH + lane * 2);
        o.x += a * vv.x;
        o.y += a * vv.y;
    }
    *(float2*)(otab + ((size_t)v * (BATCH * NCEN) + cg) * CH + lane * 2) = o;
}

// ---------------------------------------------------------------- launch
extern "C" void kernel_launch(void* const* d_in, const int* in_sizes, int n_in,
                              void* d_out, int out_size, void* d_ws, size_t ws_size,
                              hipStream_t stream) {
    (void)in_sizes; (void)n_in; (void)out_size;
    Ptr7 feats;
    for (int i = 0; i < 7; i++) feats.p[i] = (const float*)d_in[i];
    const float* awq = (const float*)d_in[7];
    const float* abq = (const float*)d_in[8];
    const float* awk = (const float*)d_in[9];
    const float* abk = (const float*)d_in[10];
    const float* awv = (const float*)d_in[11];
    const float* abv = (const float*)d_in[12];
    const float* mw1 = (const float*)d_in[13];
    const float* mb1 = (const float*)d_in[14];
    const float* mw2 = (const float*)d_in[15];
    const float* mb2 = (const float*)d_in[16];
    const float* xyz = feats.p[0];

    char* ws = (char*)d_ws;
    size_t SZ_D = (size_t)BATCH * NPTS * NPTS * 4;       // 134 MB
    float* D = (float*)ws;
    float* ktab = (float*)ws;                            // overlays D (dead by then)
    float* vtab = (float*)(ws + (size_t)7 * BATCH * NPTS * CH * 4);
    size_t off = SZ_D;
    float* xx = (float*)(ws + off); off += (size_t)BATCH * NPTS * 4;
    unsigned* adjb = (unsigned*)(ws + off); off += (size_t)BATCH * NPTS * NW * 4;
    int* fpsidx = (int*)(ws + off); off += (size_t)BATCH * NCEN * 4;
    int* idxsel = (int*)(ws + off); off += (size_t)BATCH * NCEN * NNEI * 4;
    int* gatherC = (int*)(ws + off); off += (size_t)BATCH * NCEN * 4;
    float* qtab = (float*)(ws + off); off += (size_t)7 * BATCH * NCEN * CH * 4;
    float* otab = (float*)(ws + off); off += (size_t)7 * BATCH * NCEN * CH * 4;
    float* htab = (float*)(ws + off); off += (size_t)7 * BATCH * NCEN * CHO * 4;
    if (ws_size < off) return;

    xx_kernel<<<dim3((BATCH * NPTS + 255) / 256), dim3(256), 0, stream>>>(xyz, xx);
    dmat_kernel<<<dim3(NPTS / 64, NPTS / 64, BATCH), dim3(256), 0, stream>>>(xyz, xx, D);
    knn_fps_kernel<<<dim3(BATCH + BATCH * NPTS), dim3(256), 0, stream>>>(D, adjb, fpsidx);
    make_gather<<<dim3((BATCH * NCEN + 255) / 256), dim3(256), 0, stream>>>(fpsidx, gatherC);
    reach_top32_kernel<<<dim3(NCEN, BATCH), dim3(256), 0, stream>>>(adjb, D, fpsidx, idxsel);
    // D dead: ktab/vtab overlay it
    kvproj_kernel<<<dim3(BATCH * NPTS / 64, 4, 7), dim3(256), 0, stream>>>(feats, awk, abk, awv, abv, ktab, vtab);
    qproj_kernel<<<dim3(BATCH * NCEN / 64, 2, 7), dim3(256), 0, stream>>>(feats, awq, abq, gatherC, qtab);
    attn_kernel<<<dim3(BATCH * NCEN / 4, 7), dim3(256), 0, stream>>>(qtab, ktab, vtab, idxsel, otab);
    mlp1_kernel<<<dim3(BATCH * NCEN / 64, 4, 7), dim3(256), 0, stream>>>(otab, mw1, mb1, htab);
    mlp2_kernel<<<dim3(BATCH * NCEN / 64, 4, 7), dim3(256), 0, stream>>>(htab, mw2, mb2, (float*)d_out);
}

// Round 15
// 1152.167 us; speedup vs baseline: 1.2707x; 1.0081x over previous
//
#include <hip/hip_runtime.h>
#include <hip/hip_bf16.h>
#include <math.h>

// Problem constants
constexpr int BATCH = 8;
constexpr int NPTS  = 2048;
constexpr int CH    = 128;
constexpr int CHO   = 256;
constexpr int NCEN  = 512;
constexpr int NNEI  = 32;   // n_near
constexpr int NTOP  = 11;   // n_stepk + 1
constexpr int NW    = 64;   // bitset words per row (2048/32)
constexpr int SMEM_BYTES = 17408;   // max(fps 8KB, top11 10.3KB, gemm 17.4KB)

struct Ptr7 { const float* p[7]; };

// ---------------------------------------------------------------- xx = sum(x^2)
__global__ __launch_bounds__(256) void xx_kernel(const float* __restrict__ x,
                                                 float* __restrict__ xx) {
    int p = blockIdx.x * 256 + threadIdx.x;
    if (p >= BATCH * NPTS) return;
    const float4* xr = (const float4*)(x + (size_t)p * CH);
    float s = 0.f;
#pragma unroll
    for (int i = 0; i < CH / 4; i++) {
        float4 v = xr[i];
        s += v.x * v.x + v.y * v.y + v.z * v.z + v.w * v.w;
    }
    xx[p] = s;
}

// ---------------------------------------------------------------- D = xx_i + xx_j - 2*dot
__global__ __launch_bounds__(256) void dmat_kernel(const float* __restrict__ x,
                                                   const float* __restrict__ xx,
                                                   float* __restrict__ D) {
    __shared__ float As[32][68];
    __shared__ float Bs[32][68];
    int bz = blockIdx.z;
    int i0 = blockIdx.y * 64, j0 = blockIdx.x * 64;
    const float* X = x + (size_t)bz * NPTS * CH;
    int t = threadIdx.x, tx = t & 15, ty = t >> 4;
    int lr = t >> 3, lc = (t & 7) * 4;
    const float* ai0 = X + (size_t)(i0 + lr) * CH;
    const float* ai1 = X + (size_t)(i0 + lr + 32) * CH;
    const float* bj0 = X + (size_t)(j0 + lr) * CH;
    const float* bj1 = X + (size_t)(j0 + lr + 32) * CH;
    float acc[4][4] = {};
    for (int kc = 0; kc < CH; kc += 32) {
        float4 a0 = *(const float4*)(ai0 + kc + lc);
        float4 a1 = *(const float4*)(ai1 + kc + lc);
        float4 b0 = *(const float4*)(bj0 + kc + lc);
        float4 b1 = *(const float4*)(bj1 + kc + lc);
        __syncthreads();
        As[lc + 0][lr] = a0.x; As[lc + 1][lr] = a0.y; As[lc + 2][lr] = a0.z; As[lc + 3][lr] = a0.w;
        As[lc + 0][lr + 32] = a1.x; As[lc + 1][lr + 32] = a1.y; As[lc + 2][lr + 32] = a1.z; As[lc + 3][lr + 32] = a1.w;
        Bs[lc + 0][lr] = b0.x; Bs[lc + 1][lr] = b0.y; Bs[lc + 2][lr] = b0.z; Bs[lc + 3][lr] = b0.w;
        Bs[lc + 0][lr + 32] = b1.x; Bs[lc + 1][lr + 32] = b1.y; Bs[lc + 2][lr + 32] = b1.z; Bs[lc + 3][lr + 32] = b1.w;
        __syncthreads();
#pragma unroll
        for (int kk = 0; kk < 32; kk++) {
            float4 av = *(const float4*)&As[kk][ty * 4];
            float4 bv = *(const float4*)&Bs[kk][tx * 4];
            float a[4] = {av.x, av.y, av.z, av.w};
            float b[4] = {bv.x, bv.y, bv.z, bv.w};
#pragma unroll
            for (int i = 0; i < 4; i++)
#pragma unroll
                for (int j = 0; j < 4; j++) acc[i][j] += a[i] * b[j];
        }
    }
    const float* xxb = xx + bz * NPTS;
    float xi[4], xj[4];
#pragma unroll
    for (int i = 0; i < 4; i++) xi[i] = xxb[i0 + ty * 4 + i];
#pragma unroll
    for (int j = 0; j < 4; j++) xj[j] = xxb[j0 + tx * 4 + j];
#pragma unroll
    for (int i = 0; i < 4; i++) {
        float4 o;
        o.x = xi[i] + xj[0] - 2.f * acc[i][0];
        o.y = xi[i] + xj[1] - 2.f * acc[i][1];
        o.z = xi[i] + xj[2] - 2.f * acc[i][2];
        o.w = xi[i] + xj[3] - 2.f * acc[i][3];
        *(float4*)(D + ((size_t)bz * NPTS + i0 + ty * 4 + i) * NPTS + j0 + tx * 4) = o;
    }
}

// ---------------------------------------------------------------- 64x64 fp32 GEMM tile (smem arena passed in)
template <int KSIZE, bool RELU>
__device__ __forceinline__ void gemm_tile64(char* smem,
                                            const float* __restrict__ A, int lda,
                                            const int* __restrict__ gather,
                                            const float* __restrict__ W, int ldw,
                                            const float* __restrict__ bias,
                                            float* __restrict__ Out, int ldo) {
    float (*As)[68] = (float(*)[68])smem;
    float (*Ws)[68] = (float(*)[68])(smem + 32 * 68 * 4);
    int t = threadIdx.x;
    int tx = t & 15, ty = t >> 4;
    int lr = t >> 3, lc = (t & 7) * 4;
    const float* ar0 = A + (size_t)(gather ? gather[lr] : lr) * lda;
    const float* ar1 = A + (size_t)(gather ? gather[lr + 32] : lr + 32) * lda;
    float acc[4][4] = {};
    for (int kc = 0; kc < KSIZE; kc += 32) {
        float4 a0 = *(const float4*)(ar0 + kc + lc);
        float4 a1 = *(const float4*)(ar1 + kc + lc);
        float4 w0 = *(const float4*)(W + (size_t)(kc + lr) * ldw + lc);
        float4 w1 = *(const float4*)(W + (size_t)(kc + lr) * ldw + lc + 32);
        __syncthreads();
        As[lc + 0][lr] = a0.x; As[lc + 1][lr] = a0.y; As[lc + 2][lr] = a0.z; As[lc + 3][lr] = a0.w;
        As[lc + 0][lr + 32] = a1.x; As[lc + 1][lr + 32] = a1.y; As[lc + 2][lr + 32] = a1.z; As[lc + 3][lr + 32] = a1.w;
        *(float4*)&Ws[lr][lc] = w0;
        *(float4*)&Ws[lr][lc + 32] = w1;
        __syncthreads();
#pragma unroll
        for (int kk = 0; kk < 32; kk++) {
            float4 av = *(const float4*)&As[kk][ty * 4];
            float4 wv = *(const float4*)&Ws[kk][tx * 4];
            float a[4] = {av.x, av.y, av.z, av.w};
            float w[4] = {wv.x, wv.y, wv.z, wv.w};
#pragma unroll
            for (int i = 0; i < 4; i++)
#pragma unroll
                for (int j = 0; j < 4; j++) acc[i][j] += a[i] * w[j];
        }
    }
#pragma unroll
    for (int i = 0; i < 4; i++) {
        int r = ty * 4 + i;
        float4 o;
        o.x = acc[i][0] + bias[tx * 4 + 0];
        o.y = acc[i][1] + bias[tx * 4 + 1];
        o.z = acc[i][2] + bias[tx * 4 + 2];
        o.w = acc[i][3] + bias[tx * 4 + 3];
        if (RELU) {
            o.x = fmaxf(o.x, 0.f); o.y = fmaxf(o.y, 0.f);
            o.z = fmaxf(o.z, 0.f); o.w = fmaxf(o.w, 0.f);
        }
        *(float4*)(Out + (size_t)r * ldo + tx * 4) = o;
    }
}

// ---------------------------------------------------------------- fused front: fps | top11 | (kvproj when grid extends)
// blocks [0,8): fps (1 wave, LDS mind, zero barriers)
// blocks [8, 8+16384): top-11 per row
// blocks [8+16384, +7168): kvproj tiles (only launched when ktab/vtab are separate buffers)
__global__ __launch_bounds__(256) void fused_front_kernel(const float* __restrict__ D,
                                                          unsigned int* __restrict__ adj,
                                                          int* __restrict__ fps_idx,
                                                          Ptr7 feats,
                                                          const float* __restrict__ awk,
                                                          const float* __restrict__ abk,
                                                          const float* __restrict__ awv,
                                                          const float* __restrict__ abv,
                                                          float* __restrict__ ktab,
                                                          float* __restrict__ vtab) {
    __shared__ __align__(16) char smem[SMEM_BYTES];
    if (blockIdx.x < BATCH) {
        // ---------------- FPS: one wave, mind in LDS ----------------
        int lane = threadIdx.x;
        if (lane >= 64) return;
        int b = blockIdx.x;
        float4* mp = (float4*)smem;                 // 512 float4 = 2048 floats
        float4 inf4 = {INFINITY, INFINITY, INFINITY, INFINITY};
#pragma unroll
        for (int k = 0; k < 8; k++) mp[lane + 64 * k] = inf4;
        int prev = 0;
        if (lane == 0) fps_idx[b * NCEN] = 0;
        const float* Db = D + (size_t)b * NPTS * NPTS;
        for (int s = 1; s < NCEN; s++) {
            const float4* rowp = (const float4*)(Db + (size_t)prev * NPTS);
            // 8 independent global loads; low reg pressure -> all in flight
            float4 g0 = rowp[lane + 0 * 64];
            float4 g1 = rowp[lane + 1 * 64];
            float4 g2 = rowp[lane + 2 * 64];
            float4 g3 = rowp[lane + 3 * 64];
            float4 g4 = rowp[lane + 4 * 64];
            float4 g5 = rowp[lane + 5 * 64];
            float4 g6 = rowp[lane + 6 * 64];
            float4 g7 = rowp[lane + 7 * 64];
            float4 g[8] = {g0, g1, g2, g3, g4, g5, g6, g7};
            float bv = -INFINITY; int bj = NPTS;
#pragma unroll
            for (int k = 0; k < 8; k++) {
                int li = lane + 64 * k;
                float4 m = mp[li];
                m.x = fminf(m.x, g[k].x);
                m.y = fminf(m.y, g[k].y);
                m.z = fminf(m.z, g[k].z);
                m.w = fminf(m.w, g[k].w);
                mp[li] = m;
                int j0 = 4 * li;
                // ascending j -> strict > keeps lowest index on ties
                if (m.x > bv) { bv = m.x; bj = j0 + 0; }
                if (m.y > bv) { bv = m.y; bj = j0 + 1; }
                if (m.z > bv) { bv = m.z; bj = j0 + 2; }
                if (m.w > bv) { bv = m.w; bj = j0 + 3; }
            }
#pragma unroll
            for (int off = 32; off > 0; off >>= 1) {
                float ov = __shfl_xor(bv, off);
                int oj = __shfl_xor(bj, off);
                if (ov > bv || (ov == bv && oj < bj)) { bv = ov; bj = oj; }
            }
            if (lane == 0) fps_idx[b * NCEN + s] = bj;
            prev = bj;   // all lanes agree
        }
        return;
    }
    if (blockIdx.x < BATCH + BATCH * NPTS) {
        // ---------------- top-11 ----------------
        float* row = (float*)smem;                  // 2048 floats
        float* rv = row + NPTS;                     // 256
        int* ri = (int*)(rv + 256);                 // 256
        int* picks = ri + 256;                      // 12
        int rid = blockIdx.x - BATCH;
        const float* Dr = D + (size_t)rid * NPTS;
        int t = threadIdx.x;
        float4* rp = (float4*)row;
        rp[t] = ((const float4*)Dr)[t];
        rp[t + 256] = ((const float4*)Dr)[t + 256];
        __syncthreads();
        for (int it = 0; it < NTOP; it++) {
            float bv = row[t];
            int bi = t;
#pragma unroll
            for (int k = 1; k < 8; k++) {
                int j = t + (k << 8);
                float v = row[j];
                if (v < bv) { bv = v; bi = j; }
            }
            rv[t] = bv; ri[t] = bi;
            __syncthreads();
            for (int off = 128; off > 0; off >>= 1) {
                if (t < off) {
                    float ov = rv[t + off]; int oi = ri[t + off];
                    if (ov < rv[t] || (ov == rv[t] && oi < ri[t])) { rv[t] = ov; ri[t] = oi; }
                }
                __syncthreads();
            }
            if (t == 0) { picks[it] = ri[0]; row[ri[0]] = INFINITY; }
            __syncthreads();
        }
        if (t < NW) {
            unsigned w = 0;
#pragma unroll
            for (int p = 0; p < NTOP; p++) {
                int j = picks[p];
                if ((j >> 5) == t) w |= 1u << (j & 31);
            }
            adj[(size_t)rid * NW + t] = w;
        }
        return;
    }
    // ---------------- kvproj tiles ----------------
    {
        int id = blockIdx.x - BATCH - BATCH * NPTS;   // 0..7167
        int rt = id & 255;                            // 256 row tiles
        int ct = (id >> 8) & 3;                       // 4 (k0,k1,v0,v1)
        int v = id >> 10;                             // 7 branches
        bool isv = ct >= 2;
        int c2 = ct & 1;
        const float* A = feats.p[v] + (size_t)rt * 64 * CH;
        const float* W = (isv ? awv : awk) + (size_t)v * CH * CH + c2 * 64;
        const float* bias = (isv ? abv : abk) + v * CH + c2 * 64;
        float* Out = (isv ? vtab : ktab) + (size_t)v * (BATCH * NPTS) * CH + (size_t)rt * 64 * CH + c2 * 64;
        gemm_tile64<CH, false>(smem, A, CH, nullptr, W, CH, bias, Out, CH);
    }
}

// ---------------------------------------------------------------- gather indices
__global__ void make_gather(const int* __restrict__ fps_idx, int* __restrict__ gatherC) {
    int r = blockIdx.x * 256 + threadIdx.x;
    if (r >= BATCH * NCEN) return;
    int b = r >> 9, s = r & 511;
    gatherC[r] = b * NPTS + fps_idx[b * NCEN + s];
}

// ---------------------------------------------------------------- 2-hop reach + top-32 on fp32 D
__global__ __launch_bounds__(256) void reach_top32_kernel(const unsigned int* __restrict__ adj,
                                                          const float* __restrict__ D,
                                                          const int* __restrict__ fps_idx,
                                                          int* __restrict__ idx_sel) {
    __shared__ unsigned adjw[NW], R1[NW], R2[NW];
    __shared__ int lst[NPTS];
    __shared__ float dst[NPTS];
    __shared__ int cnt;
    __shared__ float rv[256];
    __shared__ int rj[256], rp[256];
    __shared__ int sel[NNEI];
    int s = blockIdx.x, b = blockIdx.y, t = threadIdx.x;
    int i = fps_idx[b * NCEN + s];
    const unsigned* arow = adj + ((size_t)(b * NPTS + i)) * NW;
    if (t < NW) { adjw[t] = arow[t]; R1[t] = arow[t]; }
    if (t == 0) cnt = 0;
    __syncthreads();
    if (t < NW) {
        unsigned w = adjw[t];
        while (w) { int bb = __ffs(w) - 1; w &= w - 1; int p = atomicAdd(&cnt, 1); lst[p] = t * 32 + bb; }
    }
    __syncthreads();
    int n1 = cnt;
    {
        int g = t >> 6, lane = t & 63;
        for (int p = g; p < n1; p += 4) {
            unsigned aw = adj[((size_t)(b * NPTS + lst[p])) * NW + lane];
            atomicOr(&R1[lane], aw);
        }
    }
    __syncthreads();
    if (t == 0) cnt = 0;
    __syncthreads();
    if (t < NW) {
        unsigned w = R1[t];
        while (w) { int bb = __ffs(w) - 1; w &= w - 1; int p = atomicAdd(&cnt, 1); lst[p] = t * 32 + bb; }
        R2[t] = adjw[t];
    }
    __syncthreads();
    int n2 = cnt;
    {
        int g = t >> 6, lane = t & 63;
        for (int p = g; p < n2; p += 4) {
            unsigned aw = adj[((size_t)(b * NPTS + lst[p])) * NW + lane];
            atomicOr(&R2[lane], aw);
        }
    }
    __syncthreads();
    if (t == 0) cnt = 0;
    __syncthreads();
    const float* Dr = D + (size_t)(b * NPTS + i) * NPTS;
    if (t < NW) {
        unsigned w = R2[t];
        while (w) {
            int bb = __ffs(w) - 1; w &= w - 1;
            int j = t * 32 + bb;
            int p = atomicAdd(&cnt, 1);
            lst[p] = j; dst[p] = Dr[j];
        }
    }
    __syncthreads();
    int L = cnt;
    int nsel = L < NNEI ? L : NNEI;
    for (int r = 0; r < nsel; r++) {
        float bv = INFINITY; int bj = 0x7fffffff, bp = -1;
        for (int p = t; p < L; p += 256) {
            float v = dst[p]; int j = lst[p];
            if (v < bv || (v == bv && j < bj)) { bv = v; bj = j; bp = p; }
        }
        rv[t] = bv; rj[t] = bj; rp[t] = bp;
        __syncthreads();
        for (int off = 128; off > 0; off >>= 1) {
            if (t < off) {
                if (rv[t + off] < rv[t] || (rv[t + off] == rv[t] && rj[t + off] < rj[t])) {
                    rv[t] = rv[t + off]; rj[t] = rj[t + off]; rp[t] = rp[t + off];
                }
            }
            __syncthreads();
        }
        if (t == 0) { sel[r] = rj[0]; dst[rp[0]] = INFINITY; }
        __syncthreads();
    }
    if (t == 0 && nsel < NNEI) {
        int r = nsel;
        for (int j = 0; j < NPTS && r < NNEI; j++)
            if (!((R2[j >> 5] >> (j & 31)) & 1)) sel[r++] = j;
    }
    __syncthreads();
    if (t < NNEI) idx_sel[((size_t)(b * NCEN + s)) * NNEI + t] = sel[t];
}

// ---------------------------------------------------------------- standalone GEMM wrappers
__global__ __launch_bounds__(256) void kvproj_kernel(Ptr7 feats, const float* __restrict__ awk,
                                                     const float* __restrict__ abk,
                                                     const float* __restrict__ awv,
                                                     const float* __restrict__ abv,
                                                     float* __restrict__ ktab,
                                                     float* __restrict__ vtab) {
    __shared__ __align__(16) char smem[SMEM_BYTES];
    int v = blockIdx.z, ct = blockIdx.y, rt = blockIdx.x;
    bool isv = ct >= 2;
    int c2 = ct & 1;
    const float* A = feats.p[v] + (size_t)rt * 64 * CH;
    const float* W = (isv ? awv : awk) + (size_t)v * CH * CH + c2 * 64;
    const float* bias = (isv ? abv : abk) + v * CH + c2 * 64;
    float* Out = (isv ? vtab : ktab) + (size_t)v * (BATCH * NPTS) * CH + (size_t)rt * 64 * CH + c2 * 64;
    gemm_tile64<CH, false>(smem, A, CH, nullptr, W, CH, bias, Out, CH);
}

__global__ __launch_bounds__(256) void qproj_kernel(Ptr7 feats, const float* __restrict__ awq,
                                                    const float* __restrict__ abq,
                                                    const int* __restrict__ gatherC,
                                                    float* __restrict__ qtab) {
    __shared__ __align__(16) char smem[SMEM_BYTES];
    int v = blockIdx.z, ct = blockIdx.y, rt = blockIdx.x;
    gemm_tile64<CH, false>(smem, feats.p[v], CH, gatherC + rt * 64,
                           awq + (size_t)v * CH * CH + ct * 64, CH,
                           abq + v * CH + ct * 64,
                           qtab + ((size_t)v * (BATCH * NCEN) + rt * 64) * CH + ct * 64, CH);
}

__global__ __launch_bounds__(256) void mlp1_kernel(const float* __restrict__ otab,
                                                   const float* __restrict__ mw1,
                                                   const float* __restrict__ mb1,
                                                   float* __restrict__ htab) {
    __shared__ __align__(16) char smem[SMEM_BYTES];
    int v = blockIdx.z, ct = blockIdx.y, rt = blockIdx.x;
    gemm_tile64<CH, true>(smem, otab + ((size_t)v * (BATCH * NCEN) + rt * 64) * CH, CH, nullptr,
                          mw1 + (size_t)v * CH * CHO + ct * 64, CHO,
                          mb1 + v * CHO + ct * 64,
                          htab + ((size_t)v * (BATCH * NCEN) + rt * 64) * CHO + ct * 64, CHO);
}

__global__ __launch_bounds__(256) void mlp2_kernel(const float* __restrict__ htab,
                                                   const float* __restrict__ mw2,
                                                   const float* __restrict__ mb2,
                                                   float* __restrict__ out) {
    __shared__ __align__(16) char smem[SMEM_BYTES];
    int v = blockIdx.z, ct = blockIdx.y, rt = blockIdx.x;
    gemm_tile64<CHO, true>(smem, htab + ((size_t)v * (BATCH * NCEN) + rt * 64) * CHO, CHO, nullptr,
                           mw2 + (size_t)v * CHO * CHO + ct * 64, CHO,
                           mb2 + v * CHO + ct * 64,
                           out + ((size_t)v * (BATCH * NCEN) + rt * 64) * CHO + ct * 64, CHO);
}

// ---------------------------------------------------------------- attention
__global__ __launch_bounds__(256) void attn_kernel(const float* __restrict__ qtab,
                                                   const float* __restrict__ ktab,
                                                   const float* __restrict__ vtab,
                                                   const int* __restrict__ idx_sel,
                                                   float* __restrict__ otab) {
    __shared__ float q_s[4][CH];
    __shared__ float attn_s[4][NNEI];
    __shared__ int jj_s[4][NNEI];
    int v = blockIdx.y;
    int t = threadIdx.x, w = t >> 6, lane = t & 63;
    int cg = blockIdx.x * 4 + w;
    int b = cg >> 9, s = cg & 511;
    const float* qr = qtab + ((size_t)v * (BATCH * NCEN) + cg) * CH;
    *(float2*)&q_s[w][lane * 2] = *(const float2*)(qr + lane * 2);
    if (lane < NNEI) jj_s[w][lane] = idx_sel[((size_t)(b * NCEN + s)) * NNEI + lane];
    __syncthreads();
    if (lane < NNEI) {
        int j = jj_s[w][lane];
        const float* kr = ktab + ((size_t)v * (BATCH * NPTS) + b * NPTS + j) * CH;
        float acc = 0.f;
#pragma unroll
        for (int c4 = 0; c4 < CH / 4; c4++) {
            float4 qv = *(const float4*)&q_s[w][c4 * 4];
            float4 kv = *(const float4*)(kr + c4 * 4);
            acc += qv.x * kv.x + qv.y * kv.y + qv.z * kv.z + qv.w * kv.w;
        }
        float sc = acc * 0.08838834764831845f;  // 1/sqrt(128)
        float m = sc;
#pragma unroll
        for (int off = 16; off > 0; off >>= 1) m = fmaxf(m, __shfl_xor(m, off, 32));
        float e = expf(sc - m);
        float sum = e;
#pragma unroll
        for (int off = 16; off > 0; off >>= 1) sum += __shfl_xor(sum, off, 32);
        attn_s[w][lane] = e / sum;
    }
    __syncthreads();
    float2 o = {0.f, 0.f};
    const float* vbase = vtab + ((size_t)v * (BATCH * NPTS) + b * NPTS) * CH;
    for (int tt = 0; tt < NNEI; tt++) {
        int j = jj_s[w][tt];
        float a = attn_s[w][tt];
        float2 vv = *(const float2*)(vbase + (size_t)j * CH + lane * 2);
        o.x += a * vv.x;
        o.y += a * vv.y;
    }
    *(float2*)(otab + ((size_t)v * (BATCH * NCEN) + cg) * CH + lane * 2) = o;
}

// ---------------------------------------------------------------- launch
extern "C" void kernel_launch(void* const* d_in, const int* in_sizes, int n_in,
                              void* d_out, int out_size, void* d_ws, size_t ws_size,
                              hipStream_t stream) {
    (void)in_sizes; (void)n_in; (void)out_size;
    Ptr7 feats;
    for (int i = 0; i < 7; i++) feats.p[i] = (const float*)d_in[i];
    const float* awq = (const float*)d_in[7];
    const float* abq = (const float*)d_in[8];
    const float* awk = (const float*)d_in[9];
    const float* abk = (const float*)d_in[10];
    const float* awv = (const float*)d_in[11];
    const float* abv = (const float*)d_in[12];
    const float* mw1 = (const float*)d_in[13];
    const float* mb1 = (const float*)d_in[14];
    const float* mw2 = (const float*)d_in[15];
    const float* mb2 = (const float*)d_in[16];
    const float* xyz = feats.p[0];

    char* ws = (char*)d_ws;
    size_t SZ_D = (size_t)BATCH * NPTS * NPTS * 4;           // 134,217,728
    size_t SZ_KV = (size_t)7 * BATCH * NPTS * CH * 4;        // 58,720,256 each
    float* D = (float*)ws;
    size_t off = SZ_D;
    float* xx = (float*)(ws + off); off += (size_t)BATCH * NPTS * 4;
    unsigned* adjb = (unsigned*)(ws + off); off += (size_t)BATCH * NPTS * NW * 4;
    int* fpsidx = (int*)(ws + off); off += (size_t)BATCH * NCEN * 4;
    int* idxsel = (int*)(ws + off); off += (size_t)BATCH * NCEN * NNEI * 4;
    int* gatherC = (int*)(ws + off); off += (size_t)BATCH * NCEN * 4;
    float* qtab = (float*)(ws + off); off += (size_t)7 * BATCH * NCEN * CH * 4;
    float* otab = (float*)(ws + off); off += (size_t)7 * BATCH * NCEN * CH * 4;
    float* htab = (float*)(ws + off); off += (size_t)7 * BATCH * NCEN * CHO * 4;
    if (ws_size < off) return;
    bool kv_sep = (ws_size >= off + 2 * SZ_KV);
    float *ktab, *vtab;
    if (kv_sep) {
        ktab = (float*)(ws + off); off += SZ_KV;
        vtab = (float*)(ws + off); off += SZ_KV;
    } else {
        ktab = (float*)ws;                    // overlay D (dead after reach)
        vtab = (float*)(ws + SZ_KV);
    }

    xx_kernel<<<dim3((BATCH * NPTS + 255) / 256), dim3(256), 0, stream>>>(xyz, xx);
    dmat_kernel<<<dim3(NPTS / 64, NPTS / 64, BATCH), dim3(256), 0, stream>>>(xyz, xx, D);
    int fused_blocks = BATCH + BATCH * NPTS + (kv_sep ? 7 * 4 * (BATCH * NPTS / 64) : 0);
    fused_front_kernel<<<dim3(fused_blocks), dim3(256), 0, stream>>>(D, adjb, fpsidx, feats,
                                                                     awk, abk, awv, abv, ktab, vtab);
    make_gather<<<dim3((BATCH * NCEN + 255) / 256), dim3(256), 0, stream>>>(fpsidx, gatherC);
    reach_top32_kernel<<<dim3(NCEN, BATCH), dim3(256), 0, stream>>>(adjb, D, fpsidx, idxsel);
    if (!kv_sep)   // overlay path: D dead only now
        kvproj_kernel<<<dim3(BATCH * NPTS / 64, 4, 7), dim3(256), 0, stream>>>(feats, awk, abk, awv, abv, ktab, vtab);
    qproj_kernel<<<dim3(BATCH * NCEN / 64, 2, 7), dim3(256), 0, stream>>>(feats, awq, abq, gatherC, qtab);
    attn_kernel<<<dim3(BATCH * NCEN / 4, 7), dim3(256), 0, stream>>>(qtab, ktab, vtab, idxsel, otab);
    mlp1_kernel<<<dim3(BATCH * NCEN / 64, 4, 7), dim3(256), 0, stream>>>(otab, mw1, mb1, htab);
    mlp2_kernel<<<dim3(BATCH * NCEN / 64, 4, 7), dim3(256), 0, stream>>>(htab, mw2, mb2, (float*)d_out);
}